// Round 9
// baseline (268.275 us; speedup 1.0000x reference)
//
#include <hip/hip_runtime.h>

// Problem constants (n_steps==64 fixed for this instance).
#define BDIM 4096
#define DX 512
#define DZ 512
#define DY 256
#define HD 2048
#define LDT 72   // padded LDS row (shorts): 144B stride, ~2-way (free) on b128

typedef __attribute__((ext_vector_type(8))) short bf16x8;   // 8 bf16 = 4 VGPRs
typedef __attribute__((ext_vector_type(4))) float f32x4;

__device__ inline unsigned short f2bf(float f) {  // RNE f32 -> bf16
    unsigned u = __float_as_uint(f);
    unsigned r = 0x7FFFu + ((u >> 16) & 1u);
    return (unsigned short)((u + r) >> 16);
}
__device__ inline float bf2f(unsigned short h) {
    return __uint_as_float(((unsigned)h) << 16);
}

// async global->LDS, 16B/lane (proven: wave-uniform base + lane*16)
#define GLDS16(g, l)                                                            \
    __builtin_amdgcn_global_load_lds((const __attribute__((address_space(1))) void*)(g), \
                                     (__attribute__((address_space(3))) void*)(l), 16, 0, 0)

// ---------------------------------------------------------------------------
// prep: one dispatch for ALL input conversions.
// jobs 0..5: flat cvt (hi, optional lo). job 6: transposed split of A.
struct PrepJobs {
    const float* src[7];
    unsigned short* hi[7];
    unsigned short* lo[7];   // null -> hi only
    int n4[7];               // flat jobs: element count / 4 ; job 6: tile count
};
__global__ __launch_bounds__(256) void prep_k(PrepJobs J) {
    const int j = blockIdx.y;
    if (j < 6) {
        const int i4 = blockIdx.x * 256 + threadIdx.x;
        if (i4 >= J.n4[j]) return;
        float4 v = ((const float4*)J.src[j])[i4];
        ushort4 h;
        h.x = f2bf(v.x); h.y = f2bf(v.y); h.z = f2bf(v.z); h.w = f2bf(v.w);
        ((ushort4*)J.hi[j])[i4] = h;
        if (J.lo[j]) {
            ushort4 l;
            l.x = f2bf(v.x - bf2f(h.x));
            l.y = f2bf(v.y - bf2f(h.y));
            l.z = f2bf(v.z - bf2f(h.z));
            l.w = f2bf(v.w - bf2f(h.w));
            ((ushort4*)J.lo[j])[i4] = l;
        }
    } else {
        // job 6: transposed split, DZ x DZ, 16x16 grid of 32x32 tiles
        if (blockIdx.x >= 256) return;
        __shared__ float t[32][33];
        const float* A = J.src[6];
        unsigned short* HT = J.hi[6];
        unsigned short* LT = J.lo[6];
        const int bx = (blockIdx.x & 15) * 32, by = (blockIdx.x >> 4) * 32;
        const int x = threadIdx.x & 31, y = threadIdx.x >> 5;  // 32x8 view
#pragma unroll
        for (int dy = 0; dy < 32; dy += 8)
            t[y + dy][x] = A[(size_t)(by + y + dy) * DZ + bx + x];
        __syncthreads();
#pragma unroll
        for (int dy = 0; dy < 32; dy += 8) {
            float v = t[x][y + dy];
            unsigned short h = f2bf(v);
            size_t o = (size_t)(bx + y + dy) * DZ + by + x;
            HT[o] = h;
            LT[o] = f2bf(v - bf2f(h));
        }
    }
}

// ---------------------------------------------------------------------------
// 64x64 NT split GEMM core (round-6-proven): C = A @ B^T (+Dadd), hi/lo split
// bf16 inputs, 3 MFMAs/pos (fp32-class). BK=64, register prefetch, padded LDS.
// EPI=0: outputs by nullness (Cf32/Chi/Clo/CThi/CTlo).
// EPI=1: Paterson-Stockmeyer e0 epilogue — acc holds A3; emit B0..B3 groups.
struct G64In { const unsigned short *Ahi, *Alo, *Bhi, *Blo; const float* Dadd; };
struct G64Out { float* Cf32; unsigned short *Chi, *Clo, *CThi, *CTlo; };
struct E0Out {
    const float* Af32;                  // A (fp32)
    const unsigned short *A2h, *A2l;    // A2 split (hi+lo reconstructs fp32-class)
    float *B0, *B1, *B2;
    unsigned short *B3h, *B3l;
};

template <int EPI>
__device__ __forceinline__ void g64_core(int bx, int by, int M, int N, int K,
                                         G64In in, G64Out o, E0Out e,
                                         unsigned short* Ash, unsigned short* Asl,
                                         unsigned short* Bsh, unsigned short* Bsl) {
    const int tid = threadIdx.x;
    const int lane = tid & 63;
    const int wave = tid >> 6;
    const int wr = wave >> 1, wc = wave & 1;
    const int row0 = by * 64, col0 = bx * 64;
    const int sr = tid >> 2;          // 0..63 stage row
    const int sk = (tid & 3) * 16;    // short offset in 64-short chunk

    const int niter = K >> 6;  // BK=64
    bf16x8 pa0, pa1, pl0, pl1, pb0, pb1, pq0, pq1;
    {
        const unsigned short* ar = in.Ahi + (size_t)(row0 + sr) * K + sk;
        const unsigned short* al = in.Alo + (size_t)(row0 + sr) * K + sk;
        const unsigned short* br = in.Bhi + (size_t)(col0 + sr) * K + sk;
        const unsigned short* bl = in.Blo + (size_t)(col0 + sr) * K + sk;
        pa0 = *(const bf16x8*)ar; pa1 = *(const bf16x8*)(ar + 8);
        pl0 = *(const bf16x8*)al; pl1 = *(const bf16x8*)(al + 8);
        pb0 = *(const bf16x8*)br; pb1 = *(const bf16x8*)(br + 8);
        pq0 = *(const bf16x8*)bl; pq1 = *(const bf16x8*)(bl + 8);
    }

    f32x4 acc[4] = {};
    const int mb = wr * 32 + (lane & 15);
    const int nb = wc * 32 + (lane & 15);

    for (int it = 0; it < niter; ++it) {
        __syncthreads();
        *(bf16x8*)&Ash[sr * LDT + sk] = pa0; *(bf16x8*)&Ash[sr * LDT + sk + 8] = pa1;
        *(bf16x8*)&Asl[sr * LDT + sk] = pl0; *(bf16x8*)&Asl[sr * LDT + sk + 8] = pl1;
        *(bf16x8*)&Bsh[sr * LDT + sk] = pb0; *(bf16x8*)&Bsh[sr * LDT + sk + 8] = pb1;
        *(bf16x8*)&Bsl[sr * LDT + sk] = pq0; *(bf16x8*)&Bsl[sr * LDT + sk + 8] = pq1;
        __syncthreads();

        {   // next-iteration prefetch (latency overlaps MFMA below)
            const int kn = (it + 1 < niter) ? ((it + 1) << 6) : 0;
            const unsigned short* ar = in.Ahi + (size_t)(row0 + sr) * K + kn + sk;
            const unsigned short* al = in.Alo + (size_t)(row0 + sr) * K + kn + sk;
            const unsigned short* br = in.Bhi + (size_t)(col0 + sr) * K + kn + sk;
            const unsigned short* bl = in.Blo + (size_t)(col0 + sr) * K + kn + sk;
            pa0 = *(const bf16x8*)ar; pa1 = *(const bf16x8*)(ar + 8);
            pl0 = *(const bf16x8*)al; pl1 = *(const bf16x8*)(al + 8);
            pb0 = *(const bf16x8*)br; pb1 = *(const bf16x8*)(br + 8);
            pq0 = *(const bf16x8*)bl; pq1 = *(const bf16x8*)(bl + 8);
        }

#pragma unroll
        for (int kh = 0; kh < 2; ++kh) {
            const int kk = kh * 32 + (lane >> 4) * 8;
            bf16x8 ah[2], alx[2], bh[2], blx[2];
#pragma unroll
            for (int t = 0; t < 2; ++t) {
                ah[t]  = *(const bf16x8*)&Ash[(mb + t * 16) * LDT + kk];
                alx[t] = *(const bf16x8*)&Asl[(mb + t * 16) * LDT + kk];
                bh[t]  = *(const bf16x8*)&Bsh[(nb + t * 16) * LDT + kk];
                blx[t] = *(const bf16x8*)&Bsl[(nb + t * 16) * LDT + kk];
            }
#pragma unroll
            for (int mt = 0; mt < 2; ++mt)
#pragma unroll
                for (int nt = 0; nt < 2; ++nt) {
                    acc[mt * 2 + nt] = __builtin_amdgcn_mfma_f32_16x16x32_bf16(
                        ah[mt], bh[nt], acc[mt * 2 + nt], 0, 0, 0);
                    acc[mt * 2 + nt] = __builtin_amdgcn_mfma_f32_16x16x32_bf16(
                        ah[mt], blx[nt], acc[mt * 2 + nt], 0, 0, 0);
                    acc[mt * 2 + nt] = __builtin_amdgcn_mfma_f32_16x16x32_bf16(
                        alx[mt], bh[nt], acc[mt * 2 + nt], 0, 0, 0);
                }
        }
    }

    // epilogue — C/D layout: col=lane&15, row=(lane>>4)*4+reg
#pragma unroll
    for (int mt = 0; mt < 2; ++mt) {
        const int grow = row0 + wr * 32 + mt * 16 + (lane >> 4) * 4;
#pragma unroll
        for (int nt = 0; nt < 2; ++nt) {
            const int gcol = col0 + wc * 32 + nt * 16 + (lane & 15);
            f32x4 a = acc[mt * 2 + nt];
            if (EPI == 1) {
                // acc = A3 tile. Build PS groups B_q = sum c_{4q+r} A^r, c_k=1/k!
#pragma unroll
                for (int i = 0; i < 4; ++i) {
                    const size_t idx = (size_t)(grow + i) * N + gcol;
                    const float di = (grow + i == gcol) ? 1.0f : 0.0f;
                    const float av = e.Af32[idx];
                    const float a2v = bf2f(e.A2h[idx]) + bf2f(e.A2l[idx]);
                    const float a3v = a[i];
                    e.B0[idx] = di + av + 0.5f * a2v + 1.6666667e-1f * a3v;
                    e.B1[idx] = 4.1666668e-2f * di + 8.3333333e-3f * av +
                                1.3888889e-3f * a2v + 1.9841270e-4f * a3v;
                    e.B2[idx] = 2.4801587e-5f * di + 2.7557319e-6f * av +
                                2.7557319e-7f * a2v + 2.5052108e-8f * a3v;
                    float b3 = 2.0876757e-9f * di + 1.6059044e-10f * av +
                               1.1470746e-11f * a2v + 7.6471637e-13f * a3v;
                    unsigned short hh = f2bf(b3);
                    e.B3h[idx] = hh;
                    e.B3l[idx] = f2bf(b3 - bf2f(hh));
                }
            } else {
                if (in.Dadd) {
#pragma unroll
                    for (int i = 0; i < 4; ++i)
                        a[i] += in.Dadd[(size_t)(grow + i) * N + gcol];
                }
                unsigned short h4[4], l4[4];
#pragma unroll
                for (int i = 0; i < 4; ++i) {
                    h4[i] = f2bf(a[i]);
                    l4[i] = f2bf(a[i] - bf2f(h4[i]));
                }
                if (o.Cf32) {
#pragma unroll
                    for (int i = 0; i < 4; ++i) o.Cf32[(size_t)(grow + i) * N + gcol] = a[i];
                }
                if (o.Chi) {
#pragma unroll
                    for (int i = 0; i < 4; ++i) o.Chi[(size_t)(grow + i) * N + gcol] = h4[i];
                }
                if (o.Clo) {
#pragma unroll
                    for (int i = 0; i < 4; ++i) o.Clo[(size_t)(grow + i) * N + gcol] = l4[i];
                }
                if (o.CThi) {
                    ushort4 u = {h4[0], h4[1], h4[2], h4[3]};
                    *(ushort4*)&o.CThi[(size_t)gcol * M + grow] = u;
                }
                if (o.CTlo) {
                    ushort4 u = {l4[0], l4[1], l4[2], l4[3]};
                    *(ushort4*)&o.CTlo[(size_t)gcol * M + grow] = u;
                }
            }
        }
    }
}

__global__ __launch_bounds__(256) void g64_one(G64In in, G64Out o, int M, int N, int K) {
    __shared__ __align__(16) unsigned short Ash[64 * LDT], Asl[64 * LDT];
    __shared__ __align__(16) unsigned short Bsh[64 * LDT], Bsl[64 * LDT];
    E0Out e = {};
    g64_core<0>(blockIdx.x, blockIdx.y, M, N, K, in, o, e, Ash, Asl, Bsh, Bsl);
}

// dual: z0 = A3 = A2@A with fused e0 epilogue; z1 = A4 = A2@A2 -> splitT.
__global__ __launch_bounds__(256) void g64_dual_e0(G64In i0, E0Out e0o,
                                                   G64In i1, G64Out o1) {
    __shared__ __align__(16) unsigned short Ash[64 * LDT], Asl[64 * LDT];
    __shared__ __align__(16) unsigned short Bsh[64 * LDT], Bsl[64 * LDT];
    if (blockIdx.z == 0) {
        G64Out on = {};
        g64_core<1>(blockIdx.x, blockIdx.y, DZ, DZ, DZ, i0, on, e0o, Ash, Asl, Bsh, Bsl);
    } else {
        E0Out en = {};
        g64_core<0>(blockIdx.x, blockIdx.y, DZ, DZ, DZ, i1, o1, en, Ash, Asl, Bsh, Bsl);
    }
}

// ---------------------------------------------------------------------------
// Big bf16 MFMA GEMM v2 (round-8-proven): 64(M)x128(N) tile, BK=32, GLDS16.
// C = A @ B^T (+bias)(relu). M%64==0, N%128==0, K%32==0.
template <int RELU, int BIAS, int OUT_BF16>
__global__ __launch_bounds__(256) void gemm_bf16_v2(int M, int N, int K,
                                                    const unsigned short* __restrict__ A,
                                                    const unsigned short* __restrict__ B,
                                                    void* __restrict__ C,
                                                    const float* __restrict__ bias) {
    __shared__ unsigned short As[64 * 32];    // [m][k]
    __shared__ unsigned short Bs[128 * 32];   // [n][k]

    const int tid = threadIdx.x;
    const int lane = tid & 63;
    const int wave = tid >> 6;
    const int wr = wave >> 1, wc = wave & 1;
    const int row0 = blockIdx.y * 64;
    const int col0 = blockIdx.x * 128;

    const int srow = lane >> 2;
    const int schunk = (lane & 3) * 8;

    f32x4 acc[2][4] = {};

    for (int k0 = 0; k0 < K; k0 += 32) {
        GLDS16(A + (size_t)(row0 + wave * 16 + srow) * K + k0 + schunk, &As[(wave * 16) * 32]);
        GLDS16(B + (size_t)(col0 + wave * 32 + srow) * K + k0 + schunk, &Bs[(wave * 32) * 32]);
        GLDS16(B + (size_t)(col0 + wave * 32 + 16 + srow) * K + k0 + schunk,
               &Bs[(wave * 32 + 16) * 32]);
        __syncthreads();

        const int kk = (lane >> 4) * 8;
        const int mbase = wr * 32 + (lane & 15);
        const int nbase = wc * 64 + (lane & 15);
        bf16x8 af[2], bf[4];
#pragma unroll
        for (int t = 0; t < 2; ++t) af[t] = *(const bf16x8*)&As[(mbase + t * 16) * 32 + kk];
#pragma unroll
        for (int t = 0; t < 4; ++t) bf[t] = *(const bf16x8*)&Bs[(nbase + t * 16) * 32 + kk];
#pragma unroll
        for (int mt = 0; mt < 2; ++mt)
#pragma unroll
            for (int nt = 0; nt < 4; ++nt)
                acc[mt][nt] = __builtin_amdgcn_mfma_f32_16x16x32_bf16(af[mt], bf[nt],
                                                                      acc[mt][nt], 0, 0, 0);
        __syncthreads();
    }

#pragma unroll
    for (int mt = 0; mt < 2; ++mt) {
        const int grow = row0 + wr * 32 + mt * 16 + (lane >> 4) * 4;
#pragma unroll
        for (int nt = 0; nt < 4; ++nt) {
            const int gcol = col0 + wc * 64 + nt * 16 + (lane & 15);
            const float bv = BIAS ? bias[gcol] : 0.0f;
#pragma unroll
            for (int i = 0; i < 4; ++i) {
                float v = acc[mt][nt][i] + bv;
                if (RELU) v = fmaxf(v, 0.0f);
                const size_t off = (size_t)(grow + i) * N + gcol;
                if (OUT_BF16)
                    ((unsigned short*)C)[off] = f2bf(v);
                else
                    ((float*)C)[off] = v;
            }
        }
    }
}

// ---------------------------------------------------------------------------
// y-GEMM: 64x64 NT bf16, BK=64 + register prefetch + padded LDS, fp32 out+bias.
__global__ __launch_bounds__(256) void gemm64nt_y(int M, int N, int K,
                                                  const unsigned short* __restrict__ A,
                                                  const unsigned short* __restrict__ B,
                                                  float* __restrict__ C,
                                                  const float* __restrict__ bias) {
    __shared__ __align__(16) unsigned short As[64 * LDT];
    __shared__ __align__(16) unsigned short Bs[64 * LDT];
    const int tid = threadIdx.x;
    const int lane = tid & 63;
    const int wave = tid >> 6;
    const int wr = wave >> 1, wc = wave & 1;
    const int row0 = blockIdx.y * 64;
    const int col0 = blockIdx.x * 64;
    const int sr = tid >> 2, sk = (tid & 3) * 16;

    const int niter = K >> 6;
    bf16x8 pa0, pa1, pb0, pb1;
    {
        const unsigned short* ar = A + (size_t)(row0 + sr) * K + sk;
        const unsigned short* br = B + (size_t)(col0 + sr) * K + sk;
        pa0 = *(const bf16x8*)ar; pa1 = *(const bf16x8*)(ar + 8);
        pb0 = *(const bf16x8*)br; pb1 = *(const bf16x8*)(br + 8);
    }

    f32x4 acc[4] = {};
    const int mb = wr * 32 + (lane & 15);
    const int nb = wc * 32 + (lane & 15);

    for (int it = 0; it < niter; ++it) {
        __syncthreads();
        *(bf16x8*)&As[sr * LDT + sk] = pa0; *(bf16x8*)&As[sr * LDT + sk + 8] = pa1;
        *(bf16x8*)&Bs[sr * LDT + sk] = pb0; *(bf16x8*)&Bs[sr * LDT + sk + 8] = pb1;
        __syncthreads();

        {
            const int kn = (it + 1 < niter) ? ((it + 1) << 6) : 0;
            const unsigned short* ar = A + (size_t)(row0 + sr) * K + kn + sk;
            const unsigned short* br = B + (size_t)(col0 + sr) * K + kn + sk;
            pa0 = *(const bf16x8*)ar; pa1 = *(const bf16x8*)(ar + 8);
            pb0 = *(const bf16x8*)br; pb1 = *(const bf16x8*)(br + 8);
        }

#pragma unroll
        for (int kh = 0; kh < 2; ++kh) {
            const int kk = kh * 32 + (lane >> 4) * 8;
            bf16x8 af[2], bf[2];
#pragma unroll
            for (int t = 0; t < 2; ++t) {
                af[t] = *(const bf16x8*)&As[(mb + t * 16) * LDT + kk];
                bf[t] = *(const bf16x8*)&Bs[(nb + t * 16) * LDT + kk];
            }
#pragma unroll
            for (int mt = 0; mt < 2; ++mt)
#pragma unroll
                for (int nt = 0; nt < 2; ++nt)
                    acc[mt * 2 + nt] = __builtin_amdgcn_mfma_f32_16x16x32_bf16(
                        af[mt], bf[nt], acc[mt * 2 + nt], 0, 0, 0);
        }
    }

#pragma unroll
    for (int mt = 0; mt < 2; ++mt) {
        const int grow = row0 + wr * 32 + mt * 16 + (lane >> 4) * 4;
#pragma unroll
        for (int nt = 0; nt < 2; ++nt) {
            const int gcol = col0 + wc * 32 + nt * 16 + (lane & 15);
            const float bv = bias ? bias[gcol] : 0.0f;
#pragma unroll
            for (int i = 0; i < 4; ++i)
                C[(size_t)(grow + i) * N + gcol] = acc[mt * 2 + nt][i] + bv;
        }
    }
}

// ---------------------------------------------------------------------------
extern "C" void kernel_launch(void* const* d_in, const int* in_sizes, int n_in,
                              void* d_out, int out_size, void* d_ws, size_t ws_size,
                              hipStream_t stream) {
    const float* X  = (const float*)d_in[0];  // [B, Dx]
    const float* P  = (const float*)d_in[1];  // [Dz, Dx]
    const float* Am = (const float*)d_in[2];  // [Dz, Dz]
    const float* W1 = (const float*)d_in[3];  // [H, Dz]
    const float* b1 = (const float*)d_in[4];
    const float* W2 = (const float*)d_in[5];  // [H, H]
    const float* b2 = (const float*)d_in[6];
    const float* W3 = (const float*)d_in[7];  // [Dy, H]
    const float* b3 = (const float*)d_in[8];
    float* out = (float*)d_out;               // [B, Dy] fp32

    const size_t S = (size_t)DZ * DZ;  // 262144

    // ---- workspace carve-up ----
    char* p = (char*)d_ws;
    auto alloc_f = [&](size_t n) { float* r = (float*)p; p += n * 4; return r; };
    auto alloc_h = [&](size_t n) { unsigned short* r = (unsigned short*)p; p += ((n * 2 + 15) & ~15ull); return r; };
    unsigned short* Xb   = alloc_h((size_t)BDIM * DX);
    unsigned short* W2b  = alloc_h((size_t)HD * HD);
    unsigned short* W3b  = alloc_h((size_t)DY * HD);
    unsigned short* W1h  = alloc_h((size_t)HD * DZ);
    unsigned short* W1l  = alloc_h((size_t)HD * DZ);
    unsigned short* Pb   = alloc_h(S);
    unsigned short* Ah   = alloc_h(S);
    unsigned short* Al   = alloc_h(S);
    unsigned short* ATh  = alloc_h(S);
    unsigned short* ATl  = alloc_h(S);
    unsigned short* A2h  = alloc_h(S);
    unsigned short* A2l  = alloc_h(S);
    unsigned short* A2Th = alloc_h(S);
    unsigned short* A2Tl = alloc_h(S);
    unsigned short* A4Th = alloc_h(S);
    unsigned short* A4Tl = alloc_h(S);
    float* B0f = alloc_f(S);
    float* B1f = alloc_f(S);
    float* B2f = alloc_f(S);
    unsigned short* B3h  = alloc_h(S);
    unsigned short* B3l  = alloc_h(S);
    unsigned short* H1h  = alloc_h(S);
    unsigned short* H1l  = alloc_h(S);
    unsigned short* H2h  = alloc_h(S);
    unsigned short* H2l  = alloc_h(S);
    unsigned short* H3Th = alloc_h(S);
    unsigned short* H3Tl = alloc_h(S);
    unsigned short* C1b  = alloc_h((size_t)HD * DZ);
    unsigned short* XPb  = alloc_h((size_t)BDIM * DZ);
    unsigned short* h1b  = alloc_h((size_t)BDIM * HD);
    unsigned short* h2b  = alloc_h((size_t)BDIM * HD);

    // ---- L1: prep — all cvts + A^T transposed split, one dispatch ----
    PrepJobs J;
    J.src[0] = X;  J.hi[0] = Xb;  J.lo[0] = nullptr; J.n4[0] = BDIM * DX / 4;
    J.src[1] = W2; J.hi[1] = W2b; J.lo[1] = nullptr; J.n4[1] = HD * HD / 4;
    J.src[2] = W3; J.hi[2] = W3b; J.lo[2] = nullptr; J.n4[2] = DY * HD / 4;
    J.src[3] = W1; J.hi[3] = W1h; J.lo[3] = W1l;     J.n4[3] = HD * DZ / 4;
    J.src[4] = Am; J.hi[4] = Ah;  J.lo[4] = Al;      J.n4[4] = (int)(S / 4);
    J.src[5] = P;  J.hi[5] = Pb;  J.lo[5] = nullptr; J.n4[5] = (int)(S / 4);
    J.src[6] = Am; J.hi[6] = ATh; J.lo[6] = ATl;     J.n4[6] = 256;
    prep_k<<<dim3(HD * HD / 4 / 256, 7), 256, 0, stream>>>(J);

    // ---- L2: XP = X @ P^T -> bf16 [B, Dz] (256 blocks, efficient shape) ----
    gemm_bf16_v2<0, 0, 1><<<dim3(DZ / 128, BDIM / 64), 256, 0, stream>>>(
        BDIM, DZ, DX, Xb, Pb, XPb, nullptr);

    dim3 g8(DZ / 64, DZ / 64);  // 64 blocks

    // ---- L3: A2 = A@A -> split + splitT ----
    {
        G64In i{Ah, Al, ATh, ATl, nullptr};
        G64Out o{nullptr, A2h, A2l, A2Th, A2Tl};
        g64_one<<<g8, 256, 0, stream>>>(i, o, DZ, DZ, DZ);
    }
    // ---- L4: dual {A3 = A2@A -> fused e0 (B0..B3) ; A4 = A2@A2 -> splitT} ----
    {
        G64In i0{A2h, A2l, ATh, ATl, nullptr};
        E0Out e0o{Am, A2h, A2l, B0f, B1f, B2f, B3h, B3l};
        G64In i1{A2h, A2l, A2Th, A2Tl, nullptr};
        G64Out o1{nullptr, nullptr, nullptr, A4Th, A4Tl};
        g64_dual_e0<<<dim3(DZ / 64, DZ / 64, 2), 256, 0, stream>>>(i0, e0o, i1, o1);
    }
    // ---- L5..L7: Horner  H3 = ((B3*A4 + B2)*A4 + B1)*A4 + B0 = expm(A) ----
    {
        G64In i{B3h, B3l, A4Th, A4Tl, B2f};
        G64Out o{nullptr, H1h, H1l, nullptr, nullptr};
        g64_one<<<g8, 256, 0, stream>>>(i, o, DZ, DZ, DZ);
    }
    {
        G64In i{H1h, H1l, A4Th, A4Tl, B1f};
        G64Out o{nullptr, H2h, H2l, nullptr, nullptr};
        g64_one<<<g8, 256, 0, stream>>>(i, o, DZ, DZ, DZ);
    }
    {
        G64In i{H2h, H2l, A4Th, A4Tl, B0f};
        G64Out o{nullptr, nullptr, nullptr, H3Th, H3Tl};  // transposed out (B-op of C1)
        g64_one<<<g8, 256, 0, stream>>>(i, o, DZ, DZ, DZ);
    }
    // ---- L8: C1 = W1 @ H3 -> bf16 hi [H, Dz] (256 blocks) ----
    {
        G64In i{W1h, W1l, H3Th, H3Tl, nullptr};
        G64Out o{nullptr, C1b, nullptr, nullptr, nullptr};
        g64_one<<<dim3(DZ / 64, HD / 64), 256, 0, stream>>>(i, o, HD, DZ, DZ);
    }

    // ---- L9: h1 = relu(XP @ C1^T + b1)  [B,H], K=Dz ----
    gemm_bf16_v2<1, 1, 1><<<dim3(HD / 128, BDIM / 64), 256, 0, stream>>>(
        BDIM, HD, DZ, XPb, C1b, h1b, b1);
    // ---- L10: h2 = relu(h1 @ W2^T + b2) [B,H] ----
    gemm_bf16_v2<1, 1, 1><<<dim3(HD / 128, BDIM / 64), 256, 0, stream>>>(
        BDIM, HD, HD, h1b, W2b, h2b, b2);
    // ---- L11: y = h2 @ W3^T + b3 (fp32 out) ----
    gemm64nt_y<<<dim3(DY / 64, BDIM / 64), 256, 0, stream>>>(
        BDIM, DY, HD, h2b, W3b, out, b3);
}

// Round 10
// 263.584 us; speedup vs baseline: 1.0178x; 1.0178x over previous
//
#include <hip/hip_runtime.h>

// Problem constants (n_steps==64 fixed for this instance).
#define BDIM 4096
#define DX 512
#define DZ 512
#define DY 256
#define HD 2048
#define LDT 72   // padded LDS row (shorts): 144B stride, ~2-way (free) on b128

typedef __attribute__((ext_vector_type(8))) short bf16x8;   // 8 bf16 = 4 VGPRs
typedef __attribute__((ext_vector_type(4))) float f32x4;

__device__ inline unsigned short f2bf(float f) {  // RNE f32 -> bf16
    unsigned u = __float_as_uint(f);
    unsigned r = 0x7FFFu + ((u >> 16) & 1u);
    return (unsigned short)((u + r) >> 16);
}
__device__ inline float bf2f(unsigned short h) {
    return __uint_as_float(((unsigned)h) << 16);
}

// async global->LDS, 16B/lane (proven: wave-uniform base + lane*16)
#define GLDS16(g, l)                                                            \
    __builtin_amdgcn_global_load_lds((const __attribute__((address_space(1))) void*)(g), \
                                     (__attribute__((address_space(3))) void*)(l), 16, 0, 0)

// ---------------------------------------------------------------------------
// prep: one dispatch for ALL input conversions.
// jobs 0..5: flat cvt (hi, optional lo). job 6: transposed split of A.
struct PrepJobs {
    const float* src[7];
    unsigned short* hi[7];
    unsigned short* lo[7];   // null -> hi only
    int n4[7];               // flat jobs: element count / 4 ; job 6: tile count
};
__global__ __launch_bounds__(256) void prep_k(PrepJobs J) {
    const int j = blockIdx.y;
    if (j < 6) {
        const int i4 = blockIdx.x * 256 + threadIdx.x;
        if (i4 >= J.n4[j]) return;
        float4 v = ((const float4*)J.src[j])[i4];
        ushort4 h;
        h.x = f2bf(v.x); h.y = f2bf(v.y); h.z = f2bf(v.z); h.w = f2bf(v.w);
        ((ushort4*)J.hi[j])[i4] = h;
        if (J.lo[j]) {
            ushort4 l;
            l.x = f2bf(v.x - bf2f(h.x));
            l.y = f2bf(v.y - bf2f(h.y));
            l.z = f2bf(v.z - bf2f(h.z));
            l.w = f2bf(v.w - bf2f(h.w));
            ((ushort4*)J.lo[j])[i4] = l;
        }
    } else {
        // job 6: transposed split, DZ x DZ, 16x16 grid of 32x32 tiles
        if (blockIdx.x >= 256) return;
        __shared__ float t[32][33];
        const float* A = J.src[6];
        unsigned short* HT = J.hi[6];
        unsigned short* LT = J.lo[6];
        const int bx = (blockIdx.x & 15) * 32, by = (blockIdx.x >> 4) * 32;
        const int x = threadIdx.x & 31, y = threadIdx.x >> 5;  // 32x8 view
#pragma unroll
        for (int dy = 0; dy < 32; dy += 8)
            t[y + dy][x] = A[(size_t)(by + y + dy) * DZ + bx + x];
        __syncthreads();
#pragma unroll
        for (int dy = 0; dy < 32; dy += 8) {
            float v = t[x][y + dy];
            unsigned short h = f2bf(v);
            size_t o = (size_t)(bx + y + dy) * DZ + by + x;
            HT[o] = h;
            LT[o] = f2bf(v - bf2f(h));
        }
    }
}

// ---------------------------------------------------------------------------
// 64x64 NT split GEMM core (round-6-proven): C = A @ B^T (+Dadd), hi/lo split
// bf16 inputs, 3 MFMAs/pos (fp32-class). BK=64, register prefetch, padded LDS.
// EPI=0: outputs by nullness (Cf32/Chi/Clo/CThi/CTlo).
// EPI=1: degree-11 Paterson-Stockmeyer epilogue — acc holds A3; emit
//        B0^T,B1^T,B2^T split (B_q = sum_r c_{4q+r} A^r, c_k = 1/k!).
struct G64In { const unsigned short *Ahi, *Alo, *Bhi, *Blo; const float* Dadd; };
struct G64Out { float* Cf32; unsigned short *Chi, *Clo, *CThi, *CTlo; };
struct E0Out {
    const float* Af32;                  // A (fp32)
    const unsigned short *A2h, *A2l;    // A2 split (hi+lo reconstructs fp32-class)
    unsigned short *B0Th, *B0Tl, *B1Th, *B1Tl, *B2Th, *B2Tl;  // transposed splits
};

template <int EPI>
__device__ __forceinline__ void g64_core(int bx, int by, int M, int N, int K,
                                         G64In in, G64Out o, E0Out e,
                                         unsigned short* Ash, unsigned short* Asl,
                                         unsigned short* Bsh, unsigned short* Bsl) {
    const int tid = threadIdx.x;
    const int lane = tid & 63;
    const int wave = tid >> 6;
    const int wr = wave >> 1, wc = wave & 1;
    const int row0 = by * 64, col0 = bx * 64;
    const int sr = tid >> 2;          // 0..63 stage row
    const int sk = (tid & 3) * 16;    // short offset in 64-short chunk

    const int niter = K >> 6;  // BK=64
    bf16x8 pa0, pa1, pl0, pl1, pb0, pb1, pq0, pq1;
    {
        const unsigned short* ar = in.Ahi + (size_t)(row0 + sr) * K + sk;
        const unsigned short* al = in.Alo + (size_t)(row0 + sr) * K + sk;
        const unsigned short* br = in.Bhi + (size_t)(col0 + sr) * K + sk;
        const unsigned short* bl = in.Blo + (size_t)(col0 + sr) * K + sk;
        pa0 = *(const bf16x8*)ar; pa1 = *(const bf16x8*)(ar + 8);
        pl0 = *(const bf16x8*)al; pl1 = *(const bf16x8*)(al + 8);
        pb0 = *(const bf16x8*)br; pb1 = *(const bf16x8*)(br + 8);
        pq0 = *(const bf16x8*)bl; pq1 = *(const bf16x8*)(bl + 8);
    }

    f32x4 acc[4] = {};
    const int mb = wr * 32 + (lane & 15);
    const int nb = wc * 32 + (lane & 15);

    for (int it = 0; it < niter; ++it) {
        __syncthreads();
        *(bf16x8*)&Ash[sr * LDT + sk] = pa0; *(bf16x8*)&Ash[sr * LDT + sk + 8] = pa1;
        *(bf16x8*)&Asl[sr * LDT + sk] = pl0; *(bf16x8*)&Asl[sr * LDT + sk + 8] = pl1;
        *(bf16x8*)&Bsh[sr * LDT + sk] = pb0; *(bf16x8*)&Bsh[sr * LDT + sk + 8] = pb1;
        *(bf16x8*)&Bsl[sr * LDT + sk] = pq0; *(bf16x8*)&Bsl[sr * LDT + sk + 8] = pq1;
        __syncthreads();

        {   // next-iteration prefetch (latency overlaps MFMA below)
            const int kn = (it + 1 < niter) ? ((it + 1) << 6) : 0;
            const unsigned short* ar = in.Ahi + (size_t)(row0 + sr) * K + kn + sk;
            const unsigned short* al = in.Alo + (size_t)(row0 + sr) * K + kn + sk;
            const unsigned short* br = in.Bhi + (size_t)(col0 + sr) * K + kn + sk;
            const unsigned short* bl = in.Blo + (size_t)(col0 + sr) * K + kn + sk;
            pa0 = *(const bf16x8*)ar; pa1 = *(const bf16x8*)(ar + 8);
            pl0 = *(const bf16x8*)al; pl1 = *(const bf16x8*)(al + 8);
            pb0 = *(const bf16x8*)br; pb1 = *(const bf16x8*)(br + 8);
            pq0 = *(const bf16x8*)bl; pq1 = *(const bf16x8*)(bl + 8);
        }

#pragma unroll
        for (int kh = 0; kh < 2; ++kh) {
            const int kk = kh * 32 + (lane >> 4) * 8;
            bf16x8 ah[2], alx[2], bh[2], blx[2];
#pragma unroll
            for (int t = 0; t < 2; ++t) {
                ah[t]  = *(const bf16x8*)&Ash[(mb + t * 16) * LDT + kk];
                alx[t] = *(const bf16x8*)&Asl[(mb + t * 16) * LDT + kk];
                bh[t]  = *(const bf16x8*)&Bsh[(nb + t * 16) * LDT + kk];
                blx[t] = *(const bf16x8*)&Bsl[(nb + t * 16) * LDT + kk];
            }
#pragma unroll
            for (int mt = 0; mt < 2; ++mt)
#pragma unroll
                for (int nt = 0; nt < 2; ++nt) {
                    acc[mt * 2 + nt] = __builtin_amdgcn_mfma_f32_16x16x32_bf16(
                        ah[mt], bh[nt], acc[mt * 2 + nt], 0, 0, 0);
                    acc[mt * 2 + nt] = __builtin_amdgcn_mfma_f32_16x16x32_bf16(
                        ah[mt], blx[nt], acc[mt * 2 + nt], 0, 0, 0);
                    acc[mt * 2 + nt] = __builtin_amdgcn_mfma_f32_16x16x32_bf16(
                        alx[mt], bh[nt], acc[mt * 2 + nt], 0, 0, 0);
                }
        }
    }

    // epilogue — C/D layout: col=lane&15, row=(lane>>4)*4+reg
#pragma unroll
    for (int mt = 0; mt < 2; ++mt) {
        const int grow = row0 + wr * 32 + mt * 16 + (lane >> 4) * 4;
#pragma unroll
        for (int nt = 0; nt < 2; ++nt) {
            const int gcol = col0 + wc * 32 + nt * 16 + (lane & 15);
            f32x4 a = acc[mt * 2 + nt];
            if (EPI == 1) {
                // acc = A3 tile. Degree-11 PS groups, emitted TRANSPOSED (B-ops).
                ushort4 h0, l0, h1v, l1v, h2v, l2v;
                unsigned short* H0 = &h0.x;  unsigned short* L0 = &l0.x;
                unsigned short* H1 = &h1v.x; unsigned short* L1 = &l1v.x;
                unsigned short* H2 = &h2v.x; unsigned short* L2 = &l2v.x;
#pragma unroll
                for (int i = 0; i < 4; ++i) {
                    const size_t idx = (size_t)(grow + i) * N + gcol;
                    const float di = (grow + i == gcol) ? 1.0f : 0.0f;
                    const float av = e.Af32[idx];
                    const float a2v = bf2f(e.A2h[idx]) + bf2f(e.A2l[idx]);
                    const float a3v = a[i];
                    float b0 = di + av + 0.5f * a2v + 1.6666667e-1f * a3v;
                    float b1 = 4.1666668e-2f * di + 8.3333333e-3f * av +
                               1.3888889e-3f * a2v + 1.9841270e-4f * a3v;
                    float b2 = 2.4801587e-5f * di + 2.7557319e-6f * av +
                               2.7557319e-7f * a2v + 2.5052108e-8f * a3v;
                    H0[i] = f2bf(b0); L0[i] = f2bf(b0 - bf2f(H0[i]));
                    H1[i] = f2bf(b1); L1[i] = f2bf(b1 - bf2f(H1[i]));
                    H2[i] = f2bf(b2); L2[i] = f2bf(b2 - bf2f(H2[i]));
                }
                const size_t to = (size_t)gcol * DZ + grow;  // transposed, rows contig
                *(ushort4*)&e.B0Th[to] = h0; *(ushort4*)&e.B0Tl[to] = l0;
                *(ushort4*)&e.B1Th[to] = h1v; *(ushort4*)&e.B1Tl[to] = l1v;
                *(ushort4*)&e.B2Th[to] = h2v; *(ushort4*)&e.B2Tl[to] = l2v;
            } else {
                if (in.Dadd) {
#pragma unroll
                    for (int i = 0; i < 4; ++i)
                        a[i] += in.Dadd[(size_t)(grow + i) * N + gcol];
                }
                unsigned short h4[4], l4[4];
#pragma unroll
                for (int i = 0; i < 4; ++i) {
                    h4[i] = f2bf(a[i]);
                    l4[i] = f2bf(a[i] - bf2f(h4[i]));
                }
                if (o.Cf32) {
#pragma unroll
                    for (int i = 0; i < 4; ++i) o.Cf32[(size_t)(grow + i) * N + gcol] = a[i];
                }
                if (o.Chi) {
#pragma unroll
                    for (int i = 0; i < 4; ++i) o.Chi[(size_t)(grow + i) * N + gcol] = h4[i];
                }
                if (o.Clo) {
#pragma unroll
                    for (int i = 0; i < 4; ++i) o.Clo[(size_t)(grow + i) * N + gcol] = l4[i];
                }
                if (o.CThi) {
                    ushort4 u = {h4[0], h4[1], h4[2], h4[3]};
                    *(ushort4*)&o.CThi[(size_t)gcol * M + grow] = u;
                }
                if (o.CTlo) {
                    ushort4 u = {l4[0], l4[1], l4[2], l4[3]};
                    *(ushort4*)&o.CTlo[(size_t)gcol * M + grow] = u;
                }
            }
        }
    }
}

__global__ __launch_bounds__(256) void g64_one(G64In in, G64Out o, int M, int N, int K) {
    __shared__ __align__(16) unsigned short Ash[64 * LDT], Asl[64 * LDT];
    __shared__ __align__(16) unsigned short Bsh[64 * LDT], Bsl[64 * LDT];
    E0Out e = {};
    g64_core<0>(blockIdx.x, blockIdx.y, M, N, K, in, o, e, Ash, Asl, Bsh, Bsl);
}

// dual: z0 = A3 = A2@A with fused degree-11 e0 epilogue; z1 = A4 = A2@A2 -> splitT.
__global__ __launch_bounds__(256) void g64_dual_e0(G64In i0, E0Out e0o,
                                                   G64In i1, G64Out o1) {
    __shared__ __align__(16) unsigned short Ash[64 * LDT], Asl[64 * LDT];
    __shared__ __align__(16) unsigned short Bsh[64 * LDT], Bsl[64 * LDT];
    if (blockIdx.z == 0) {
        G64Out on = {};
        g64_core<1>(blockIdx.x, blockIdx.y, DZ, DZ, DZ, i0, on, e0o, Ash, Asl, Bsh, Bsl);
    } else {
        E0Out en = {};
        g64_core<0>(blockIdx.x, blockIdx.y, DZ, DZ, DZ, i1, o1, en, Ash, Asl, Bsh, Bsl);
    }
}

// tri: z-batched U_q = W1 @ B_q (q=0,1,2), independent — one dispatch.
__global__ __launch_bounds__(256) void g64_tri(G64In i0, G64Out o0, G64In i1, G64Out o1,
                                               G64In i2, G64Out o2, int M, int N, int K) {
    __shared__ __align__(16) unsigned short Ash[64 * LDT], Asl[64 * LDT];
    __shared__ __align__(16) unsigned short Bsh[64 * LDT], Bsl[64 * LDT];
    E0Out e = {};
    G64In in = (blockIdx.z == 0) ? i0 : (blockIdx.z == 1) ? i1 : i2;
    G64Out o = (blockIdx.z == 0) ? o0 : (blockIdx.z == 1) ? o1 : o2;
    g64_core<0>(blockIdx.x, blockIdx.y, M, N, K, in, o, e, Ash, Asl, Bsh, Bsl);
}

// ---------------------------------------------------------------------------
// Big bf16 MFMA GEMM v2 (round-8-proven): 64(M)x128(N) tile, BK=32, GLDS16.
// C = A @ B^T (+bias)(relu). M%64==0, N%128==0, K%32==0.
template <int RELU, int BIAS, int OUT_BF16>
__global__ __launch_bounds__(256) void gemm_bf16_v2(int M, int N, int K,
                                                    const unsigned short* __restrict__ A,
                                                    const unsigned short* __restrict__ B,
                                                    void* __restrict__ C,
                                                    const float* __restrict__ bias) {
    __shared__ unsigned short As[64 * 32];    // [m][k]
    __shared__ unsigned short Bs[128 * 32];   // [n][k]

    const int tid = threadIdx.x;
    const int lane = tid & 63;
    const int wave = tid >> 6;
    const int wr = wave >> 1, wc = wave & 1;
    const int row0 = blockIdx.y * 64;
    const int col0 = blockIdx.x * 128;

    const int srow = lane >> 2;
    const int schunk = (lane & 3) * 8;

    f32x4 acc[2][4] = {};

    for (int k0 = 0; k0 < K; k0 += 32) {
        GLDS16(A + (size_t)(row0 + wave * 16 + srow) * K + k0 + schunk, &As[(wave * 16) * 32]);
        GLDS16(B + (size_t)(col0 + wave * 32 + srow) * K + k0 + schunk, &Bs[(wave * 32) * 32]);
        GLDS16(B + (size_t)(col0 + wave * 32 + 16 + srow) * K + k0 + schunk,
               &Bs[(wave * 32 + 16) * 32]);
        __syncthreads();

        const int kk = (lane >> 4) * 8;
        const int mbase = wr * 32 + (lane & 15);
        const int nbase = wc * 64 + (lane & 15);
        bf16x8 af[2], bf[4];
#pragma unroll
        for (int t = 0; t < 2; ++t) af[t] = *(const bf16x8*)&As[(mbase + t * 16) * 32 + kk];
#pragma unroll
        for (int t = 0; t < 4; ++t) bf[t] = *(const bf16x8*)&Bs[(nbase + t * 16) * 32 + kk];
#pragma unroll
        for (int mt = 0; mt < 2; ++mt)
#pragma unroll
            for (int nt = 0; nt < 4; ++nt)
                acc[mt][nt] = __builtin_amdgcn_mfma_f32_16x16x32_bf16(af[mt], bf[nt],
                                                                      acc[mt][nt], 0, 0, 0);
        __syncthreads();
    }

#pragma unroll
    for (int mt = 0; mt < 2; ++mt) {
        const int grow = row0 + wr * 32 + mt * 16 + (lane >> 4) * 4;
#pragma unroll
        for (int nt = 0; nt < 4; ++nt) {
            const int gcol = col0 + wc * 64 + nt * 16 + (lane & 15);
            const float bv = BIAS ? bias[gcol] : 0.0f;
#pragma unroll
            for (int i = 0; i < 4; ++i) {
                float v = acc[mt][nt][i] + bv;
                if (RELU) v = fmaxf(v, 0.0f);
                const size_t off = (size_t)(grow + i) * N + gcol;
                if (OUT_BF16)
                    ((unsigned short*)C)[off] = f2bf(v);
                else
                    ((float*)C)[off] = v;
            }
        }
    }
}

// ---------------------------------------------------------------------------
// y-GEMM: 64x64 NT bf16, BK=64 + register prefetch + padded LDS, fp32 out+bias.
__global__ __launch_bounds__(256) void gemm64nt_y(int M, int N, int K,
                                                  const unsigned short* __restrict__ A,
                                                  const unsigned short* __restrict__ B,
                                                  float* __restrict__ C,
                                                  const float* __restrict__ bias) {
    __shared__ __align__(16) unsigned short As[64 * LDT];
    __shared__ __align__(16) unsigned short Bs[64 * LDT];
    const int tid = threadIdx.x;
    const int lane = tid & 63;
    const int wave = tid >> 6;
    const int wr = wave >> 1, wc = wave & 1;
    const int row0 = blockIdx.y * 64;
    const int col0 = blockIdx.x * 64;
    const int sr = tid >> 2, sk = (tid & 3) * 16;

    const int niter = K >> 6;
    bf16x8 pa0, pa1, pb0, pb1;
    {
        const unsigned short* ar = A + (size_t)(row0 + sr) * K + sk;
        const unsigned short* br = B + (size_t)(col0 + sr) * K + sk;
        pa0 = *(const bf16x8*)ar; pa1 = *(const bf16x8*)(ar + 8);
        pb0 = *(const bf16x8*)br; pb1 = *(const bf16x8*)(br + 8);
    }

    f32x4 acc[4] = {};
    const int mb = wr * 32 + (lane & 15);
    const int nb = wc * 32 + (lane & 15);

    for (int it = 0; it < niter; ++it) {
        __syncthreads();
        *(bf16x8*)&As[sr * LDT + sk] = pa0; *(bf16x8*)&As[sr * LDT + sk + 8] = pa1;
        *(bf16x8*)&Bs[sr * LDT + sk] = pb0; *(bf16x8*)&Bs[sr * LDT + sk + 8] = pb1;
        __syncthreads();

        {
            const int kn = (it + 1 < niter) ? ((it + 1) << 6) : 0;
            const unsigned short* ar = A + (size_t)(row0 + sr) * K + kn + sk;
            const unsigned short* br = B + (size_t)(col0 + sr) * K + kn + sk;
            pa0 = *(const bf16x8*)ar; pa1 = *(const bf16x8*)(ar + 8);
            pb0 = *(const bf16x8*)br; pb1 = *(const bf16x8*)(br + 8);
        }

#pragma unroll
        for (int kh = 0; kh < 2; ++kh) {
            const int kk = kh * 32 + (lane >> 4) * 8;
            bf16x8 af[2], bf[2];
#pragma unroll
            for (int t = 0; t < 2; ++t) {
                af[t] = *(const bf16x8*)&As[(mb + t * 16) * LDT + kk];
                bf[t] = *(const bf16x8*)&Bs[(nb + t * 16) * LDT + kk];
            }
#pragma unroll
            for (int mt = 0; mt < 2; ++mt)
#pragma unroll
                for (int nt = 0; nt < 2; ++nt)
                    acc[mt * 2 + nt] = __builtin_amdgcn_mfma_f32_16x16x32_bf16(
                        af[mt], bf[nt], acc[mt * 2 + nt], 0, 0, 0);
        }
    }

#pragma unroll
    for (int mt = 0; mt < 2; ++mt) {
        const int grow = row0 + wr * 32 + mt * 16 + (lane >> 4) * 4;
#pragma unroll
        for (int nt = 0; nt < 2; ++nt) {
            const int gcol = col0 + wc * 32 + nt * 16 + (lane & 15);
            const float bv = bias ? bias[gcol] : 0.0f;
#pragma unroll
            for (int i = 0; i < 4; ++i)
                C[(size_t)(grow + i) * N + gcol] = acc[mt * 2 + nt][i] + bv;
        }
    }
}

// ---------------------------------------------------------------------------
extern "C" void kernel_launch(void* const* d_in, const int* in_sizes, int n_in,
                              void* d_out, int out_size, void* d_ws, size_t ws_size,
                              hipStream_t stream) {
    const float* X  = (const float*)d_in[0];  // [B, Dx]
    const float* P  = (const float*)d_in[1];  // [Dz, Dx]
    const float* Am = (const float*)d_in[2];  // [Dz, Dz]
    const float* W1 = (const float*)d_in[3];  // [H, Dz]
    const float* b1 = (const float*)d_in[4];
    const float* W2 = (const float*)d_in[5];  // [H, H]
    const float* b2 = (const float*)d_in[6];
    const float* W3 = (const float*)d_in[7];  // [Dy, H]
    const float* b3 = (const float*)d_in[8];
    float* out = (float*)d_out;               // [B, Dy] fp32

    const size_t S = (size_t)DZ * DZ;       // 262144
    const size_t SW = (size_t)HD * DZ;      // 1048576 (W1 / U / V / C1 shapes)

    // ---- workspace carve-up ----
    char* p = (char*)d_ws;
    auto alloc_f = [&](size_t n) { float* r = (float*)p; p += n * 4; return r; };
    auto alloc_h = [&](size_t n) { unsigned short* r = (unsigned short*)p; p += ((n * 2 + 15) & ~15ull); return r; };
    unsigned short* Xb   = alloc_h((size_t)BDIM * DX);
    unsigned short* W2b  = alloc_h((size_t)HD * HD);
    unsigned short* W3b  = alloc_h((size_t)DY * HD);
    unsigned short* W1h  = alloc_h(SW);
    unsigned short* W1l  = alloc_h(SW);
    unsigned short* Pb   = alloc_h(S);
    unsigned short* Ah   = alloc_h(S);
    unsigned short* Al   = alloc_h(S);
    unsigned short* ATh  = alloc_h(S);
    unsigned short* ATl  = alloc_h(S);
    unsigned short* A2h  = alloc_h(S);
    unsigned short* A2l  = alloc_h(S);
    unsigned short* A2Th = alloc_h(S);
    unsigned short* A2Tl = alloc_h(S);
    unsigned short* A4Th = alloc_h(S);
    unsigned short* A4Tl = alloc_h(S);
    unsigned short* B0Th = alloc_h(S);
    unsigned short* B0Tl = alloc_h(S);
    unsigned short* B1Th = alloc_h(S);
    unsigned short* B1Tl = alloc_h(S);
    unsigned short* B2Th = alloc_h(S);
    unsigned short* B2Tl = alloc_h(S);
    float* U0f = alloc_f(SW);
    float* U1f = alloc_f(SW);
    unsigned short* U2h  = alloc_h(SW);
    unsigned short* U2l  = alloc_h(SW);
    unsigned short* Vh   = alloc_h(SW);
    unsigned short* Vl   = alloc_h(SW);
    unsigned short* C1b  = alloc_h(SW);
    unsigned short* XPb  = alloc_h((size_t)BDIM * DZ);
    unsigned short* h1b  = alloc_h((size_t)BDIM * HD);
    unsigned short* h2b  = alloc_h((size_t)BDIM * HD);

    // ---- L1: prep — all cvts + A^T transposed split, one dispatch ----
    PrepJobs J;
    J.src[0] = X;  J.hi[0] = Xb;  J.lo[0] = nullptr; J.n4[0] = BDIM * DX / 4;
    J.src[1] = W2; J.hi[1] = W2b; J.lo[1] = nullptr; J.n4[1] = HD * HD / 4;
    J.src[2] = W3; J.hi[2] = W3b; J.lo[2] = nullptr; J.n4[2] = DY * HD / 4;
    J.src[3] = W1; J.hi[3] = W1h; J.lo[3] = W1l;     J.n4[3] = (int)(SW / 4);
    J.src[4] = Am; J.hi[4] = Ah;  J.lo[4] = Al;      J.n4[4] = (int)(S / 4);
    J.src[5] = P;  J.hi[5] = Pb;  J.lo[5] = nullptr; J.n4[5] = (int)(S / 4);
    J.src[6] = Am; J.hi[6] = ATh; J.lo[6] = ATl;     J.n4[6] = 256;
    prep_k<<<dim3(HD * HD / 4 / 256, 7), 256, 0, stream>>>(J);

    // ---- L2: XP = X @ P^T -> bf16 [B, Dz] ----
    gemm_bf16_v2<0, 0, 1><<<dim3(DZ / 128, BDIM / 64), 256, 0, stream>>>(
        BDIM, DZ, DX, Xb, Pb, XPb, nullptr);

    dim3 g8(DZ / 64, DZ / 64);  // 64 blocks

    // ---- L3 (d1): A2 = A@A -> split + splitT ----
    {
        G64In i{Ah, Al, ATh, ATl, nullptr};
        G64Out o{nullptr, A2h, A2l, A2Th, A2Tl};
        g64_one<<<g8, 256, 0, stream>>>(i, o, DZ, DZ, DZ);
    }
    // ---- L4 (d2): dual { A3 = A2@A -> fused e0 (B0^T..B2^T) ; A4 = A2@A2 -> splitT }
    {
        G64In i0{A2h, A2l, ATh, ATl, nullptr};
        E0Out e0o{Am, A2h, A2l, B0Th, B0Tl, B1Th, B1Tl, B2Th, B2Tl};
        G64In i1{A2h, A2l, A2Th, A2Tl, nullptr};
        G64Out o1{nullptr, nullptr, nullptr, A4Th, A4Tl};
        g64_dual_e0<<<dim3(DZ / 64, DZ / 64, 2), 256, 0, stream>>>(i0, e0o, i1, o1);
    }
    // ---- L5 (d3): z3 batch  U_q = W1 @ B_q  [H, Dz] (768 blocks) ----
    {
        G64In i0{W1h, W1l, B0Th, B0Tl, nullptr};
        G64Out o0{U0f, nullptr, nullptr, nullptr, nullptr};
        G64In i1{W1h, W1l, B1Th, B1Tl, nullptr};
        G64Out o1{U1f, nullptr, nullptr, nullptr, nullptr};
        G64In i2{W1h, W1l, B2Th, B2Tl, nullptr};
        G64Out o2{nullptr, U2h, U2l, nullptr, nullptr};
        g64_tri<<<dim3(DZ / 64, HD / 64, 3), 256, 0, stream>>>(i0, o0, i1, o1, i2, o2,
                                                               HD, DZ, DZ);
    }
    // ---- L6 (d4): V = U2@A4 + U1  [H, Dz] (256 blocks) ----
    {
        G64In i{U2h, U2l, A4Th, A4Tl, U1f};
        G64Out o{nullptr, Vh, Vl, nullptr, nullptr};
        g64_one<<<dim3(DZ / 64, HD / 64), 256, 0, stream>>>(i, o, HD, DZ, DZ);
    }
    // ---- L7 (d5): C1 = V@A4 + U0 = W1·exp(A)  [H, Dz] (256 blocks) ----
    {
        G64In i{Vh, Vl, A4Th, A4Tl, U0f};
        G64Out o{nullptr, C1b, nullptr, nullptr, nullptr};
        g64_one<<<dim3(DZ / 64, HD / 64), 256, 0, stream>>>(i, o, HD, DZ, DZ);
    }

    // ---- L8: h1 = relu(XP @ C1^T + b1)  [B,H], K=Dz ----
    gemm_bf16_v2<1, 1, 1><<<dim3(HD / 128, BDIM / 64), 256, 0, stream>>>(
        BDIM, HD, DZ, XPb, C1b, h1b, b1);
    // ---- L9: h2 = relu(h1 @ W2^T + b2) [B,H] ----
    gemm_bf16_v2<1, 1, 1><<<dim3(HD / 128, BDIM / 64), 256, 0, stream>>>(
        BDIM, HD, HD, h1b, W2b, h2b, b2);
    // ---- L10: y = h2 @ W3^T + b3 (fp32 out) ----
    gemm64nt_y<<<dim3(DY / 64, BDIM / 64), 256, 0, stream>>>(
        BDIM, DY, HD, h2b, W3b, out, b3);
}

// Round 11
// 258.587 us; speedup vs baseline: 1.0375x; 1.0193x over previous
//
#include <hip/hip_runtime.h>

// Problem constants (n_steps==64 fixed for this instance).
#define BDIM 4096
#define DX 512
#define DZ 512
#define DY 256
#define HD 2048
#define LDT 72   // padded LDS row (shorts): 144B stride, ~2-way (free) on b128

typedef __attribute__((ext_vector_type(8))) short bf16x8;   // 8 bf16 = 4 VGPRs
typedef __attribute__((ext_vector_type(4))) float f32x4;

__device__ inline unsigned short f2bf(float f) {  // RNE f32 -> bf16
    unsigned u = __float_as_uint(f);
    unsigned r = 0x7FFFu + ((u >> 16) & 1u);
    return (unsigned short)((u + r) >> 16);
}
__device__ inline float bf2f(unsigned short h) {
    return __uint_as_float(((unsigned)h) << 16);
}

// async global->LDS, 16B/lane (proven: wave-uniform base + lane*16)
#define GLDS16(g, l)                                                            \
    __builtin_amdgcn_global_load_lds((const __attribute__((address_space(1))) void*)(g), \
                                     (__attribute__((address_space(3))) void*)(l), 16, 0, 0)

// ---------------------------------------------------------------------------
// prep: one dispatch for ALL input conversions.
// jobs 0..5: flat cvt (hi, optional lo). job 6: transposed split of A.
struct PrepJobs {
    const float* src[7];
    unsigned short* hi[7];
    unsigned short* lo[7];   // null -> hi only
    int n4[7];               // flat jobs: element count / 4 ; job 6: tile count
};
__global__ __launch_bounds__(256) void prep_k(PrepJobs J) {
    const int j = blockIdx.y;
    if (j < 6) {
        const int i4 = blockIdx.x * 256 + threadIdx.x;
        if (i4 >= J.n4[j]) return;
        float4 v = ((const float4*)J.src[j])[i4];
        ushort4 h;
        h.x = f2bf(v.x); h.y = f2bf(v.y); h.z = f2bf(v.z); h.w = f2bf(v.w);
        ((ushort4*)J.hi[j])[i4] = h;
        if (J.lo[j]) {
            ushort4 l;
            l.x = f2bf(v.x - bf2f(h.x));
            l.y = f2bf(v.y - bf2f(h.y));
            l.z = f2bf(v.z - bf2f(h.z));
            l.w = f2bf(v.w - bf2f(h.w));
            ((ushort4*)J.lo[j])[i4] = l;
        }
    } else {
        // job 6: transposed split, DZ x DZ, 16x16 grid of 32x32 tiles
        if (blockIdx.x >= 256) return;
        __shared__ float t[32][33];
        const float* A = J.src[6];
        unsigned short* HT = J.hi[6];
        unsigned short* LT = J.lo[6];
        const int bx = (blockIdx.x & 15) * 32, by = (blockIdx.x >> 4) * 32;
        const int x = threadIdx.x & 31, y = threadIdx.x >> 5;  // 32x8 view
#pragma unroll
        for (int dy = 0; dy < 32; dy += 8)
            t[y + dy][x] = A[(size_t)(by + y + dy) * DZ + bx + x];
        __syncthreads();
#pragma unroll
        for (int dy = 0; dy < 32; dy += 8) {
            float v = t[x][y + dy];
            unsigned short h = f2bf(v);
            size_t o = (size_t)(bx + y + dy) * DZ + by + x;
            HT[o] = h;
            LT[o] = f2bf(v - bf2f(h));
        }
    }
}

// ---------------------------------------------------------------------------
// 64x64 NT split GEMM building blocks (round-6-proven loop, verbatim).
struct G64In { const unsigned short *Ahi, *Alo, *Bhi, *Blo; const float* Dadd; };
struct G64Out { float* Cf32; unsigned short *Chi, *Clo, *CThi, *CTlo; };
struct E0Out {
    const float* Af32;                  // A (fp32)
    const unsigned short *A2h, *A2l;    // A2 split (hi+lo reconstructs fp32-class)
    unsigned short *B0Th, *B0Tl, *B1Th, *B1Tl, *B2Th, *B2Tl;  // transposed splits
};

// K-loop: accumulate C_tile += A[rows row0..+64, :K] @ B[rows col0..+64, :K]^T
__device__ __forceinline__ void g64_kloop(G64In in, int row0, int col0, int K,
                                          f32x4 (&acc)[4], int sr, int sk, int mb, int nb,
                                          unsigned short* Ash, unsigned short* Asl,
                                          unsigned short* Bsh, unsigned short* Bsl) {
    const int niter = K >> 6;  // BK=64
    bf16x8 pa0, pa1, pl0, pl1, pb0, pb1, pq0, pq1;
    {
        const unsigned short* ar = in.Ahi + (size_t)(row0 + sr) * K + sk;
        const unsigned short* al = in.Alo + (size_t)(row0 + sr) * K + sk;
        const unsigned short* br = in.Bhi + (size_t)(col0 + sr) * K + sk;
        const unsigned short* bl = in.Blo + (size_t)(col0 + sr) * K + sk;
        pa0 = *(const bf16x8*)ar; pa1 = *(const bf16x8*)(ar + 8);
        pl0 = *(const bf16x8*)al; pl1 = *(const bf16x8*)(al + 8);
        pb0 = *(const bf16x8*)br; pb1 = *(const bf16x8*)(br + 8);
        pq0 = *(const bf16x8*)bl; pq1 = *(const bf16x8*)(bl + 8);
    }

    for (int it = 0; it < niter; ++it) {
        __syncthreads();
        *(bf16x8*)&Ash[sr * LDT + sk] = pa0; *(bf16x8*)&Ash[sr * LDT + sk + 8] = pa1;
        *(bf16x8*)&Asl[sr * LDT + sk] = pl0; *(bf16x8*)&Asl[sr * LDT + sk + 8] = pl1;
        *(bf16x8*)&Bsh[sr * LDT + sk] = pb0; *(bf16x8*)&Bsh[sr * LDT + sk + 8] = pb1;
        *(bf16x8*)&Bsl[sr * LDT + sk] = pq0; *(bf16x8*)&Bsl[sr * LDT + sk + 8] = pq1;
        __syncthreads();

        {   // next-iteration prefetch (latency overlaps MFMA below)
            const int kn = (it + 1 < niter) ? ((it + 1) << 6) : 0;
            const unsigned short* ar = in.Ahi + (size_t)(row0 + sr) * K + kn + sk;
            const unsigned short* al = in.Alo + (size_t)(row0 + sr) * K + kn + sk;
            const unsigned short* br = in.Bhi + (size_t)(col0 + sr) * K + kn + sk;
            const unsigned short* bl = in.Blo + (size_t)(col0 + sr) * K + kn + sk;
            pa0 = *(const bf16x8*)ar; pa1 = *(const bf16x8*)(ar + 8);
            pl0 = *(const bf16x8*)al; pl1 = *(const bf16x8*)(al + 8);
            pb0 = *(const bf16x8*)br; pb1 = *(const bf16x8*)(br + 8);
            pq0 = *(const bf16x8*)bl; pq1 = *(const bf16x8*)(bl + 8);
        }

#pragma unroll
        for (int kh = 0; kh < 2; ++kh) {
            const int kk = kh * 32 + (threadIdx.x >> 4 & 3) * 8;
            bf16x8 ah[2], alx[2], bh[2], blx[2];
#pragma unroll
            for (int t = 0; t < 2; ++t) {
                ah[t]  = *(const bf16x8*)&Ash[(mb + t * 16) * LDT + kk];
                alx[t] = *(const bf16x8*)&Asl[(mb + t * 16) * LDT + kk];
                bh[t]  = *(const bf16x8*)&Bsh[(nb + t * 16) * LDT + kk];
                blx[t] = *(const bf16x8*)&Bsl[(nb + t * 16) * LDT + kk];
            }
#pragma unroll
            for (int mt = 0; mt < 2; ++mt)
#pragma unroll
                for (int nt = 0; nt < 2; ++nt) {
                    acc[mt * 2 + nt] = __builtin_amdgcn_mfma_f32_16x16x32_bf16(
                        ah[mt], bh[nt], acc[mt * 2 + nt], 0, 0, 0);
                    acc[mt * 2 + nt] = __builtin_amdgcn_mfma_f32_16x16x32_bf16(
                        ah[mt], blx[nt], acc[mt * 2 + nt], 0, 0, 0);
                    acc[mt * 2 + nt] = __builtin_amdgcn_mfma_f32_16x16x32_bf16(
                        alx[mt], bh[nt], acc[mt * 2 + nt], 0, 0, 0);
                }
        }
    }
}

// Full GEMM tile: kloop + epilogue. EPI=0: outputs by nullness.
// EPI=1: degree-11 PS epilogue — acc holds A3; emit B0^T..B2^T splits.
template <int EPI>
__device__ __forceinline__ void g64_core(int bx, int by, int M, int N, int K,
                                         G64In in, G64Out o, E0Out e,
                                         unsigned short* Ash, unsigned short* Asl,
                                         unsigned short* Bsh, unsigned short* Bsl) {
    const int tid = threadIdx.x;
    const int lane = tid & 63;
    const int wave = tid >> 6;
    const int wr = wave >> 1, wc = wave & 1;
    const int row0 = by * 64, col0 = bx * 64;
    const int sr = tid >> 2;
    const int sk = (tid & 3) * 16;
    const int mb = wr * 32 + (lane & 15);
    const int nb = wc * 32 + (lane & 15);

    f32x4 acc[4] = {};
    g64_kloop(in, row0, col0, K, acc, sr, sk, mb, nb, Ash, Asl, Bsh, Bsl);

    // epilogue — C/D layout: col=lane&15, row=(lane>>4)*4+reg
#pragma unroll
    for (int mt = 0; mt < 2; ++mt) {
        const int grow = row0 + wr * 32 + mt * 16 + (lane >> 4) * 4;
#pragma unroll
        for (int nt = 0; nt < 2; ++nt) {
            const int gcol = col0 + wc * 32 + nt * 16 + (lane & 15);
            f32x4 a = acc[mt * 2 + nt];
            if (EPI == 1) {
                ushort4 h0, l0, h1v, l1v, h2v, l2v;
                unsigned short* H0 = &h0.x;  unsigned short* L0 = &l0.x;
                unsigned short* H1 = &h1v.x; unsigned short* L1 = &l1v.x;
                unsigned short* H2 = &h2v.x; unsigned short* L2 = &l2v.x;
#pragma unroll
                for (int i = 0; i < 4; ++i) {
                    const size_t idx = (size_t)(grow + i) * N + gcol;
                    const float di = (grow + i == gcol) ? 1.0f : 0.0f;
                    const float av = e.Af32[idx];
                    const float a2v = bf2f(e.A2h[idx]) + bf2f(e.A2l[idx]);
                    const float a3v = a[i];
                    float b0 = di + av + 0.5f * a2v + 1.6666667e-1f * a3v;
                    float b1 = 4.1666668e-2f * di + 8.3333333e-3f * av +
                               1.3888889e-3f * a2v + 1.9841270e-4f * a3v;
                    float b2 = 2.4801587e-5f * di + 2.7557319e-6f * av +
                               2.7557319e-7f * a2v + 2.5052108e-8f * a3v;
                    H0[i] = f2bf(b0); L0[i] = f2bf(b0 - bf2f(H0[i]));
                    H1[i] = f2bf(b1); L1[i] = f2bf(b1 - bf2f(H1[i]));
                    H2[i] = f2bf(b2); L2[i] = f2bf(b2 - bf2f(H2[i]));
                }
                const size_t to = (size_t)gcol * DZ + grow;  // transposed, rows contig
                *(ushort4*)&e.B0Th[to] = h0; *(ushort4*)&e.B0Tl[to] = l0;
                *(ushort4*)&e.B1Th[to] = h1v; *(ushort4*)&e.B1Tl[to] = l1v;
                *(ushort4*)&e.B2Th[to] = h2v; *(ushort4*)&e.B2Tl[to] = l2v;
            } else {
                if (in.Dadd) {
#pragma unroll
                    for (int i = 0; i < 4; ++i)
                        a[i] += in.Dadd[(size_t)(grow + i) * N + gcol];
                }
                unsigned short h4[4], l4[4];
#pragma unroll
                for (int i = 0; i < 4; ++i) {
                    h4[i] = f2bf(a[i]);
                    l4[i] = f2bf(a[i] - bf2f(h4[i]));
                }
                if (o.Cf32) {
#pragma unroll
                    for (int i = 0; i < 4; ++i) o.Cf32[(size_t)(grow + i) * N + gcol] = a[i];
                }
                if (o.Chi) {
#pragma unroll
                    for (int i = 0; i < 4; ++i) o.Chi[(size_t)(grow + i) * N + gcol] = h4[i];
                }
                if (o.Clo) {
#pragma unroll
                    for (int i = 0; i < 4; ++i) o.Clo[(size_t)(grow + i) * N + gcol] = l4[i];
                }
                if (o.CThi) {
                    ushort4 u = {h4[0], h4[1], h4[2], h4[3]};
                    *(ushort4*)&o.CThi[(size_t)gcol * M + grow] = u;
                }
                if (o.CTlo) {
                    ushort4 u = {l4[0], l4[1], l4[2], l4[3]};
                    *(ushort4*)&o.CTlo[(size_t)gcol * M + grow] = u;
                }
            }
        }
    }
}

// ---------------------------------------------------------------------------
// Big bf16 MFMA GEMM core (round-8-proven): 64(M)x128(N) tile, BK=32, GLDS16.
template <int RELU, int BIAS, int OUT_BF16>
__device__ __forceinline__ void bigemm_core(int bxi, int byi, int M, int N, int K,
                                            const unsigned short* __restrict__ A,
                                            const unsigned short* __restrict__ B,
                                            void* __restrict__ C,
                                            const float* __restrict__ bias,
                                            unsigned short* As, unsigned short* Bs) {
    const int tid = threadIdx.x;
    const int lane = tid & 63;
    const int wave = tid >> 6;
    const int wr = wave >> 1, wc = wave & 1;
    const int row0 = byi * 64;
    const int col0 = bxi * 128;

    const int srow = lane >> 2;
    const int schunk = (lane & 3) * 8;

    f32x4 acc[2][4] = {};

    for (int k0 = 0; k0 < K; k0 += 32) {
        GLDS16(A + (size_t)(row0 + wave * 16 + srow) * K + k0 + schunk, &As[(wave * 16) * 32]);
        GLDS16(B + (size_t)(col0 + wave * 32 + srow) * K + k0 + schunk, &Bs[(wave * 32) * 32]);
        GLDS16(B + (size_t)(col0 + wave * 32 + 16 + srow) * K + k0 + schunk,
               &Bs[(wave * 32 + 16) * 32]);
        __syncthreads();

        const int kk = (lane >> 4) * 8;
        const int mbase = wr * 32 + (lane & 15);
        const int nbase = wc * 64 + (lane & 15);
        bf16x8 af[2], bf[4];
#pragma unroll
        for (int t = 0; t < 2; ++t) af[t] = *(const bf16x8*)&As[(mbase + t * 16) * 32 + kk];
#pragma unroll
        for (int t = 0; t < 4; ++t) bf[t] = *(const bf16x8*)&Bs[(nbase + t * 16) * 32 + kk];
#pragma unroll
        for (int mt = 0; mt < 2; ++mt)
#pragma unroll
            for (int nt = 0; nt < 4; ++nt)
                acc[mt][nt] = __builtin_amdgcn_mfma_f32_16x16x32_bf16(af[mt], bf[nt],
                                                                      acc[mt][nt], 0, 0, 0);
        __syncthreads();
    }

#pragma unroll
    for (int mt = 0; mt < 2; ++mt) {
        const int grow = row0 + wr * 32 + mt * 16 + (lane >> 4) * 4;
#pragma unroll
        for (int nt = 0; nt < 4; ++nt) {
            const int gcol = col0 + wc * 64 + nt * 16 + (lane & 15);
            const float bv = BIAS ? bias[gcol] : 0.0f;
#pragma unroll
            for (int i = 0; i < 4; ++i) {
                float v = acc[mt][nt][i] + bv;
                if (RELU) v = fmaxf(v, 0.0f);
                const size_t off = (size_t)(grow + i) * N + gcol;
                if (OUT_BF16)
                    ((unsigned short*)C)[off] = f2bf(v);
                else
                    ((float*)C)[off] = v;
            }
        }
    }
}

template <int RELU, int BIAS, int OUT_BF16>
__global__ __launch_bounds__(256) void gemm_bf16_v2(int M, int N, int K,
                                                    const unsigned short* __restrict__ A,
                                                    const unsigned short* __restrict__ B,
                                                    void* __restrict__ C,
                                                    const float* __restrict__ bias) {
    __shared__ unsigned short As[64 * 32];
    __shared__ unsigned short Bs[128 * 32];
    bigemm_core<RELU, BIAS, OUT_BF16>(blockIdx.x, blockIdx.y, M, N, K, A, B, C, bias, As, Bs);
}

// ---------------------------------------------------------------------------
// combo: z=0 -> XP = X @ P^T (256 blocks); z=1 -> A2 = A@A split+splitT (64).
__global__ __launch_bounds__(256) void combo_k(const unsigned short* Xb,
                                               const unsigned short* Pb,
                                               unsigned short* XPb,
                                               G64In ia, G64Out oa) {
    __shared__ __align__(16) unsigned short smem[4 * 64 * LDT];
    if (blockIdx.z == 0) {
        if (blockIdx.x >= DZ / 128) return;  // 4 x 64 active
        bigemm_core<0, 0, 1>(blockIdx.x, blockIdx.y, BDIM, DZ, DX, Xb, Pb, XPb, nullptr,
                             smem, smem + 64 * 32);
    } else {
        if (blockIdx.x >= 8 || blockIdx.y >= 8) return;
        E0Out e = {};
        g64_core<0>(blockIdx.x, blockIdx.y, DZ, DZ, DZ, ia, oa, e,
                    smem, smem + 64 * LDT, smem + 128 * LDT, smem + 192 * LDT);
    }
}

// dual (d2): z0 = A3 = A2@A with fused e0 epilogue; z1 = A4 = A2@A2 -> split+splitT.
__global__ __launch_bounds__(256) void g64_dual_e0(G64In i0, E0Out e0o,
                                                   G64In i1, G64Out o1) {
    __shared__ __align__(16) unsigned short Ash[64 * LDT], Asl[64 * LDT];
    __shared__ __align__(16) unsigned short Bsh[64 * LDT], Bsl[64 * LDT];
    if (blockIdx.z == 0) {
        G64Out on = {};
        g64_core<1>(blockIdx.x, blockIdx.y, DZ, DZ, DZ, i0, on, e0o, Ash, Asl, Bsh, Bsl);
    } else {
        E0Out en = {};
        g64_core<0>(blockIdx.x, blockIdx.y, DZ, DZ, DZ, i1, o1, en, Ash, Asl, Bsh, Bsl);
    }
}

// quad (d3): z in {0,1,2}: U_q = W1 @ B_q (8x32 grid); z=3: A8 = A4@A4 -> splitT (8x8).
__global__ __launch_bounds__(256) void g64_quad(G64In i0, G64Out o0, G64In i1, G64Out o1,
                                                G64In i2, G64Out o2, G64In i3, G64Out o3) {
    __shared__ __align__(16) unsigned short Ash[64 * LDT], Asl[64 * LDT];
    __shared__ __align__(16) unsigned short Bsh[64 * LDT], Bsl[64 * LDT];
    const int z = blockIdx.z;
    if (z == 3 && blockIdx.y >= 8) return;
    G64In in = (z == 0) ? i0 : (z == 1) ? i1 : (z == 2) ? i2 : i3;
    G64Out o = (z == 0) ? o0 : (z == 1) ? o1 : (z == 2) ? o2 : o3;
    const int M = (z < 3) ? HD : DZ;  // M only affects CT stride (A8 uses compact DZ)
    E0Out e = {};
    g64_core<0>(blockIdx.x, blockIdx.y, M, DZ, DZ, in, o, e, Ash, Asl, Bsh, Bsl);
}

// d4: C1 = U0 + U1@A4^T' + U2@A8^T'  (dual-K: two kloop passes), bf16-hi out.
__global__ __launch_bounds__(256) void g64_c1(G64In s1, G64In s2,
                                              const float* __restrict__ U0,
                                              unsigned short* __restrict__ C1b) {
    __shared__ __align__(16) unsigned short Ash[64 * LDT], Asl[64 * LDT];
    __shared__ __align__(16) unsigned short Bsh[64 * LDT], Bsl[64 * LDT];
    const int tid = threadIdx.x;
    const int lane = tid & 63;
    const int wave = tid >> 6;
    const int wr = wave >> 1, wc = wave & 1;
    const int row0 = blockIdx.y * 64, col0 = blockIdx.x * 64;
    const int sr = tid >> 2, sk = (tid & 3) * 16;
    const int mb = wr * 32 + (lane & 15);
    const int nb = wc * 32 + (lane & 15);

    f32x4 acc[4] = {};
    g64_kloop(s1, row0, col0, DZ, acc, sr, sk, mb, nb, Ash, Asl, Bsh, Bsl);
    g64_kloop(s2, row0, col0, DZ, acc, sr, sk, mb, nb, Ash, Asl, Bsh, Bsl);

#pragma unroll
    for (int mt = 0; mt < 2; ++mt) {
        const int grow = row0 + wr * 32 + mt * 16 + (lane >> 4) * 4;
#pragma unroll
        for (int nt = 0; nt < 2; ++nt) {
            const int gcol = col0 + wc * 32 + nt * 16 + (lane & 15);
#pragma unroll
            for (int i = 0; i < 4; ++i) {
                const size_t idx = (size_t)(grow + i) * DZ + gcol;
                C1b[idx] = f2bf(acc[mt * 2 + nt][i] + U0[idx]);
            }
        }
    }
}

// ---------------------------------------------------------------------------
// y-GEMM: 64x64 NT bf16, BK=64 + register prefetch + padded LDS, fp32 out+bias.
__global__ __launch_bounds__(256) void gemm64nt_y(int M, int N, int K,
                                                  const unsigned short* __restrict__ A,
                                                  const unsigned short* __restrict__ B,
                                                  float* __restrict__ C,
                                                  const float* __restrict__ bias) {
    __shared__ __align__(16) unsigned short As[64 * LDT];
    __shared__ __align__(16) unsigned short Bs[64 * LDT];
    const int tid = threadIdx.x;
    const int lane = tid & 63;
    const int wave = tid >> 6;
    const int wr = wave >> 1, wc = wave & 1;
    const int row0 = blockIdx.y * 64;
    const int col0 = blockIdx.x * 64;
    const int sr = tid >> 2, sk = (tid & 3) * 16;

    const int niter = K >> 6;
    bf16x8 pa0, pa1, pb0, pb1;
    {
        const unsigned short* ar = A + (size_t)(row0 + sr) * K + sk;
        const unsigned short* br = B + (size_t)(col0 + sr) * K + sk;
        pa0 = *(const bf16x8*)ar; pa1 = *(const bf16x8*)(ar + 8);
        pb0 = *(const bf16x8*)br; pb1 = *(const bf16x8*)(br + 8);
    }

    f32x4 acc[4] = {};
    const int mb = wr * 32 + (lane & 15);
    const int nb = wc * 32 + (lane & 15);

    for (int it = 0; it < niter; ++it) {
        __syncthreads();
        *(bf16x8*)&As[sr * LDT + sk] = pa0; *(bf16x8*)&As[sr * LDT + sk + 8] = pa1;
        *(bf16x8*)&Bs[sr * LDT + sk] = pb0; *(bf16x8*)&Bs[sr * LDT + sk + 8] = pb1;
        __syncthreads();

        {
            const int kn = (it + 1 < niter) ? ((it + 1) << 6) : 0;
            const unsigned short* ar = A + (size_t)(row0 + sr) * K + kn + sk;
            const unsigned short* br = B + (size_t)(col0 + sr) * K + kn + sk;
            pa0 = *(const bf16x8*)ar; pa1 = *(const bf16x8*)(ar + 8);
            pb0 = *(const bf16x8*)br; pb1 = *(const bf16x8*)(br + 8);
        }

#pragma unroll
        for (int kh = 0; kh < 2; ++kh) {
            const int kk = kh * 32 + (lane >> 4) * 8;
            bf16x8 af[2], bf[2];
#pragma unroll
            for (int t = 0; t < 2; ++t) {
                af[t] = *(const bf16x8*)&As[(mb + t * 16) * LDT + kk];
                bf[t] = *(const bf16x8*)&Bs[(nb + t * 16) * LDT + kk];
            }
#pragma unroll
            for (int mt = 0; mt < 2; ++mt)
#pragma unroll
                for (int nt = 0; nt < 2; ++nt)
                    acc[mt * 2 + nt] = __builtin_amdgcn_mfma_f32_16x16x32_bf16(
                        af[mt], bf[nt], acc[mt * 2 + nt], 0, 0, 0);
        }
    }

#pragma unroll
    for (int mt = 0; mt < 2; ++mt) {
        const int grow = row0 + wr * 32 + mt * 16 + (lane >> 4) * 4;
#pragma unroll
        for (int nt = 0; nt < 2; ++nt) {
            const int gcol = col0 + wc * 32 + nt * 16 + (lane & 15);
            const float bv = bias ? bias[gcol] : 0.0f;
#pragma unroll
            for (int i = 0; i < 4; ++i)
                C[(size_t)(grow + i) * N + gcol] = acc[mt * 2 + nt][i] + bv;
        }
    }
}

// ---------------------------------------------------------------------------
extern "C" void kernel_launch(void* const* d_in, const int* in_sizes, int n_in,
                              void* d_out, int out_size, void* d_ws, size_t ws_size,
                              hipStream_t stream) {
    const float* X  = (const float*)d_in[0];  // [B, Dx]
    const float* P  = (const float*)d_in[1];  // [Dz, Dx]
    const float* Am = (const float*)d_in[2];  // [Dz, Dz]
    const float* W1 = (const float*)d_in[3];  // [H, Dz]
    const float* b1 = (const float*)d_in[4];
    const float* W2 = (const float*)d_in[5];  // [H, H]
    const float* b2 = (const float*)d_in[6];
    const float* W3 = (const float*)d_in[7];  // [Dy, H]
    const float* b3 = (const float*)d_in[8];
    float* out = (float*)d_out;               // [B, Dy] fp32

    const size_t S = (size_t)DZ * DZ;       // 262144
    const size_t SW = (size_t)HD * DZ;      // 1048576

    // ---- workspace carve-up (~73.5 MB; U0f aliases dead A/A2 region) ----
    char* p = (char*)d_ws;
    auto alloc_h = [&](size_t n) { unsigned short* r = (unsigned short*)p; p += ((n * 2 + 15) & ~15ull); return r; };
    unsigned short* Xb   = alloc_h((size_t)BDIM * DX);
    unsigned short* W2b  = alloc_h((size_t)HD * HD);
    unsigned short* W3b  = alloc_h((size_t)DY * HD);
    unsigned short* W1h  = alloc_h(SW);
    unsigned short* W1l  = alloc_h(SW);
    unsigned short* Pb   = alloc_h(S);
    unsigned short* Ah   = alloc_h(S);   // |--- 4 MB contiguous group, dead after d2:
    unsigned short* Al   = alloc_h(S);   // |
    unsigned short* ATh  = alloc_h(S);   // |
    unsigned short* ATl  = alloc_h(S);   // |
    unsigned short* A2h  = alloc_h(S);   // |
    unsigned short* A2l  = alloc_h(S);   // |
    unsigned short* A2Th = alloc_h(S);   // |
    unsigned short* A2Tl = alloc_h(S);   // |--- U0f aliases this whole group (d3+)
    unsigned short* A4h  = alloc_h(S);
    unsigned short* A4l  = alloc_h(S);
    unsigned short* A4Th = alloc_h(S);
    unsigned short* A4Tl = alloc_h(S);
    unsigned short* A8Th = alloc_h(S);
    unsigned short* A8Tl = alloc_h(S);
    unsigned short* B0Th = alloc_h(S);
    unsigned short* B0Tl = alloc_h(S);
    unsigned short* B1Th = alloc_h(S);
    unsigned short* B1Tl = alloc_h(S);
    unsigned short* B2Th = alloc_h(S);
    unsigned short* B2Tl = alloc_h(S);
    unsigned short* U1h  = alloc_h(SW);
    unsigned short* U1l  = alloc_h(SW);
    unsigned short* U2h  = alloc_h(SW);
    unsigned short* U2l  = alloc_h(SW);
    unsigned short* C1b  = alloc_h(SW);
    unsigned short* XPb  = alloc_h((size_t)BDIM * DZ);
    unsigned short* h1b  = alloc_h((size_t)BDIM * HD);
    unsigned short* h2b  = alloc_h((size_t)BDIM * HD);
    float* U0f = (float*)Ah;  // 4 MB alias: written in d3, after A/A2 are dead

    // ---- L1: prep — all cvts + A^T transposed split, one dispatch ----
    PrepJobs J;
    J.src[0] = X;  J.hi[0] = Xb;  J.lo[0] = nullptr; J.n4[0] = BDIM * DX / 4;
    J.src[1] = W2; J.hi[1] = W2b; J.lo[1] = nullptr; J.n4[1] = HD * HD / 4;
    J.src[2] = W3; J.hi[2] = W3b; J.lo[2] = nullptr; J.n4[2] = DY * HD / 4;
    J.src[3] = W1; J.hi[3] = W1h; J.lo[3] = W1l;     J.n4[3] = (int)(SW / 4);
    J.src[4] = Am; J.hi[4] = Ah;  J.lo[4] = Al;      J.n4[4] = (int)(S / 4);
    J.src[5] = P;  J.hi[5] = Pb;  J.lo[5] = nullptr; J.n4[5] = (int)(S / 4);
    J.src[6] = Am; J.hi[6] = ATh; J.lo[6] = ATl;     J.n4[6] = 256;
    prep_k<<<dim3(HD * HD / 4 / 256, 7), 256, 0, stream>>>(J);

    // ---- L2: combo { XP = X@P^T (256 blk) || A2 = A@A -> split+splitT (64 blk) } ----
    {
        G64In ia{Ah, Al, ATh, ATl, nullptr};
        G64Out oa{nullptr, A2h, A2l, A2Th, A2Tl};
        combo_k<<<dim3(8, BDIM / 64, 2), 256, 0, stream>>>(Xb, Pb, XPb, ia, oa);
    }
    // ---- L3 (d2): dual { A3 = A2@A -> fused e0 (B0^T..B2^T) ; A4 = A2@A2 -> split+splitT }
    {
        G64In i0{A2h, A2l, ATh, ATl, nullptr};
        E0Out e0o{Am, A2h, A2l, B0Th, B0Tl, B1Th, B1Tl, B2Th, B2Tl};
        G64In i1{A2h, A2l, A2Th, A2Tl, nullptr};
        G64Out o1{nullptr, A4h, A4l, A4Th, A4Tl};
        g64_dual_e0<<<dim3(DZ / 64, DZ / 64, 2), 256, 0, stream>>>(i0, e0o, i1, o1);
    }
    // ---- L4 (d3): quad { U0, U1, U2 = W1@B_q (768 blk) ; A8 = A4@A4 -> splitT (64) }
    {
        G64In i0{W1h, W1l, B0Th, B0Tl, nullptr};
        G64Out o0{U0f, nullptr, nullptr, nullptr, nullptr};
        G64In i1{W1h, W1l, B1Th, B1Tl, nullptr};
        G64Out o1{nullptr, U1h, U1l, nullptr, nullptr};
        G64In i2{W1h, W1l, B2Th, B2Tl, nullptr};
        G64Out o2{nullptr, U2h, U2l, nullptr, nullptr};
        G64In i3{A4h, A4l, A4Th, A4Tl, nullptr};
        G64Out o3{nullptr, nullptr, nullptr, A8Th, A8Tl};
        g64_quad<<<dim3(DZ / 64, HD / 64, 4), 256, 0, stream>>>(i0, o0, i1, o1, i2, o2, i3, o3);
    }
    // ---- L5 (d4): C1 = U0 + U1@A4 + U2@A8 = W1·exp(A)  (256 blk, dual-K) ----
    {
        G64In s1{U1h, U1l, A4Th, A4Tl, nullptr};
        G64In s2{U2h, U2l, A8Th, A8Tl, nullptr};
        g64_c1<<<dim3(DZ / 64, HD / 64), 256, 0, stream>>>(s1, s2, U0f, C1b);
    }

    // ---- L6: h1 = relu(XP @ C1^T + b1)  [B,H], K=Dz ----
    gemm_bf16_v2<1, 1, 1><<<dim3(HD / 128, BDIM / 64), 256, 0, stream>>>(
        BDIM, HD, DZ, XPb, C1b, h1b, b1);
    // ---- L7: h2 = relu(h1 @ W2^T + b2) [B,H] ----
    gemm_bf16_v2<1, 1, 1><<<dim3(HD / 128, BDIM / 64), 256, 0, stream>>>(
        BDIM, HD, HD, h1b, W2b, h2b, b2);
    // ---- L8: y = h2 @ W3^T + b3 (fp32 out) ----
    gemm64nt_y<<<dim3(DY / 64, BDIM / 64), 256, 0, stream>>>(
        BDIM, DY, HD, h2b, W3b, out, b3);
}

// Round 12
// 251.265 us; speedup vs baseline: 1.0677x; 1.0291x over previous
//
#include <hip/hip_runtime.h>

// Problem constants (n_steps==64 fixed for this instance).
#define BDIM 4096
#define DX 512
#define DZ 512
#define DY 256
#define HD 2048
#define LDT 72   // padded LDS row (shorts): 144B stride, ~2-way (free) on b128

typedef __attribute__((ext_vector_type(8))) short bf16x8;   // 8 bf16 = 4 VGPRs
typedef __attribute__((ext_vector_type(4))) float f32x4;

__device__ inline unsigned short f2bf(float f) {  // RNE f32 -> bf16
    unsigned u = __float_as_uint(f);
    unsigned r = 0x7FFFu + ((u >> 16) & 1u);
    return (unsigned short)((u + r) >> 16);
}
__device__ inline float bf2f(unsigned short h) {
    return __uint_as_float(((unsigned)h) << 16);
}

// async global->LDS, 16B/lane (proven: wave-uniform base + lane*16)
#define GLDS16(g, l)                                                            \
    __builtin_amdgcn_global_load_lds((const __attribute__((address_space(1))) void*)(g), \
                                     (__attribute__((address_space(3))) void*)(l), 16, 0, 0)

// ---------------------------------------------------------------------------
// prep: one dispatch for ALL input conversions.
struct PrepJobs {
    const float* src[7];
    unsigned short* hi[7];
    unsigned short* lo[7];   // null -> hi only
    int n4[7];
};
__global__ __launch_bounds__(256) void prep_k(PrepJobs J) {
    const int j = blockIdx.y;
    if (j < 6) {
        const int i4 = blockIdx.x * 256 + threadIdx.x;
        if (i4 >= J.n4[j]) return;
        float4 v = ((const float4*)J.src[j])[i4];
        ushort4 h;
        h.x = f2bf(v.x); h.y = f2bf(v.y); h.z = f2bf(v.z); h.w = f2bf(v.w);
        ((ushort4*)J.hi[j])[i4] = h;
        if (J.lo[j]) {
            ushort4 l;
            l.x = f2bf(v.x - bf2f(h.x));
            l.y = f2bf(v.y - bf2f(h.y));
            l.z = f2bf(v.z - bf2f(h.z));
            l.w = f2bf(v.w - bf2f(h.w));
            ((ushort4*)J.lo[j])[i4] = l;
        }
    } else {
        if (blockIdx.x >= 256) return;
        __shared__ float t[32][33];
        const float* A = J.src[6];
        unsigned short* HT = J.hi[6];
        unsigned short* LT = J.lo[6];
        const int bx = (blockIdx.x & 15) * 32, by = (blockIdx.x >> 4) * 32;
        const int x = threadIdx.x & 31, y = threadIdx.x >> 5;
#pragma unroll
        for (int dy = 0; dy < 32; dy += 8)
            t[y + dy][x] = A[(size_t)(by + y + dy) * DZ + bx + x];
        __syncthreads();
#pragma unroll
        for (int dy = 0; dy < 32; dy += 8) {
            float v = t[x][y + dy];
            unsigned short h = f2bf(v);
            size_t o = (size_t)(bx + y + dy) * DZ + by + x;
            HT[o] = h;
            LT[o] = f2bf(v - bf2f(h));
        }
    }
}

// ---------------------------------------------------------------------------
// 64x64 NT split GEMM building blocks (round-6-proven loop, verbatim).
struct G64In { const unsigned short *Ahi, *Alo, *Bhi, *Blo; const float* Dadd; };
struct G64Out { float* Cf32; unsigned short *Chi, *Clo, *CThi, *CTlo; };
struct E0Out {
    const float* Af32;
    const unsigned short *A2h, *A2l;
    unsigned short *B0Th, *B0Tl, *B1Th, *B1Tl, *B2Th, *B2Tl;
};

__device__ __forceinline__ void g64_kloop(G64In in, int row0, int col0, int K,
                                          f32x4 (&acc)[4], int sr, int sk, int mb, int nb,
                                          unsigned short* Ash, unsigned short* Asl,
                                          unsigned short* Bsh, unsigned short* Bsl) {
    const int niter = K >> 6;  // BK=64
    bf16x8 pa0, pa1, pl0, pl1, pb0, pb1, pq0, pq1;
    {
        const unsigned short* ar = in.Ahi + (size_t)(row0 + sr) * K + sk;
        const unsigned short* al = in.Alo + (size_t)(row0 + sr) * K + sk;
        const unsigned short* br = in.Bhi + (size_t)(col0 + sr) * K + sk;
        const unsigned short* bl = in.Blo + (size_t)(col0 + sr) * K + sk;
        pa0 = *(const bf16x8*)ar; pa1 = *(const bf16x8*)(ar + 8);
        pl0 = *(const bf16x8*)al; pl1 = *(const bf16x8*)(al + 8);
        pb0 = *(const bf16x8*)br; pb1 = *(const bf16x8*)(br + 8);
        pq0 = *(const bf16x8*)bl; pq1 = *(const bf16x8*)(bl + 8);
    }

    for (int it = 0; it < niter; ++it) {
        __syncthreads();
        *(bf16x8*)&Ash[sr * LDT + sk] = pa0; *(bf16x8*)&Ash[sr * LDT + sk + 8] = pa1;
        *(bf16x8*)&Asl[sr * LDT + sk] = pl0; *(bf16x8*)&Asl[sr * LDT + sk + 8] = pl1;
        *(bf16x8*)&Bsh[sr * LDT + sk] = pb0; *(bf16x8*)&Bsh[sr * LDT + sk + 8] = pb1;
        *(bf16x8*)&Bsl[sr * LDT + sk] = pq0; *(bf16x8*)&Bsl[sr * LDT + sk + 8] = pq1;
        __syncthreads();

        {   // next-iteration prefetch (latency overlaps MFMA below)
            const int kn = (it + 1 < niter) ? ((it + 1) << 6) : 0;
            const unsigned short* ar = in.Ahi + (size_t)(row0 + sr) * K + kn + sk;
            const unsigned short* al = in.Alo + (size_t)(row0 + sr) * K + kn + sk;
            const unsigned short* br = in.Bhi + (size_t)(col0 + sr) * K + kn + sk;
            const unsigned short* bl = in.Blo + (size_t)(col0 + sr) * K + kn + sk;
            pa0 = *(const bf16x8*)ar; pa1 = *(const bf16x8*)(ar + 8);
            pl0 = *(const bf16x8*)al; pl1 = *(const bf16x8*)(al + 8);
            pb0 = *(const bf16x8*)br; pb1 = *(const bf16x8*)(br + 8);
            pq0 = *(const bf16x8*)bl; pq1 = *(const bf16x8*)(bl + 8);
        }

#pragma unroll
        for (int kh = 0; kh < 2; ++kh) {
            const int kk = kh * 32 + (threadIdx.x >> 4 & 3) * 8;
            bf16x8 ah[2], alx[2], bh[2], blx[2];
#pragma unroll
            for (int t = 0; t < 2; ++t) {
                ah[t]  = *(const bf16x8*)&Ash[(mb + t * 16) * LDT + kk];
                alx[t] = *(const bf16x8*)&Asl[(mb + t * 16) * LDT + kk];
                bh[t]  = *(const bf16x8*)&Bsh[(nb + t * 16) * LDT + kk];
                blx[t] = *(const bf16x8*)&Bsl[(nb + t * 16) * LDT + kk];
            }
#pragma unroll
            for (int mt = 0; mt < 2; ++mt)
#pragma unroll
                for (int nt = 0; nt < 2; ++nt) {
                    acc[mt * 2 + nt] = __builtin_amdgcn_mfma_f32_16x16x32_bf16(
                        ah[mt], bh[nt], acc[mt * 2 + nt], 0, 0, 0);
                    acc[mt * 2 + nt] = __builtin_amdgcn_mfma_f32_16x16x32_bf16(
                        ah[mt], blx[nt], acc[mt * 2 + nt], 0, 0, 0);
                    acc[mt * 2 + nt] = __builtin_amdgcn_mfma_f32_16x16x32_bf16(
                        alx[mt], bh[nt], acc[mt * 2 + nt], 0, 0, 0);
                }
        }
    }
}

template <int EPI>
__device__ __forceinline__ void g64_core(int bx, int by, int M, int N, int K,
                                         G64In in, G64Out o, E0Out e,
                                         unsigned short* Ash, unsigned short* Asl,
                                         unsigned short* Bsh, unsigned short* Bsl) {
    const int tid = threadIdx.x;
    const int lane = tid & 63;
    const int wave = tid >> 6;
    const int wr = wave >> 1, wc = wave & 1;
    const int row0 = by * 64, col0 = bx * 64;
    const int sr = tid >> 2;
    const int sk = (tid & 3) * 16;
    const int mb = wr * 32 + (lane & 15);
    const int nb = wc * 32 + (lane & 15);

    f32x4 acc[4] = {};
    g64_kloop(in, row0, col0, K, acc, sr, sk, mb, nb, Ash, Asl, Bsh, Bsl);

#pragma unroll
    for (int mt = 0; mt < 2; ++mt) {
        const int grow = row0 + wr * 32 + mt * 16 + (lane >> 4) * 4;
#pragma unroll
        for (int nt = 0; nt < 2; ++nt) {
            const int gcol = col0 + wc * 32 + nt * 16 + (lane & 15);
            f32x4 a = acc[mt * 2 + nt];
            if (EPI == 1) {
                ushort4 h0, l0, h1v, l1v, h2v, l2v;
                unsigned short* H0 = &h0.x;  unsigned short* L0 = &l0.x;
                unsigned short* H1 = &h1v.x; unsigned short* L1 = &l1v.x;
                unsigned short* H2 = &h2v.x; unsigned short* L2 = &l2v.x;
#pragma unroll
                for (int i = 0; i < 4; ++i) {
                    const size_t idx = (size_t)(grow + i) * N + gcol;
                    const float di = (grow + i == gcol) ? 1.0f : 0.0f;
                    const float av = e.Af32[idx];
                    const float a2v = bf2f(e.A2h[idx]) + bf2f(e.A2l[idx]);
                    const float a3v = a[i];
                    float b0 = di + av + 0.5f * a2v + 1.6666667e-1f * a3v;
                    float b1 = 4.1666668e-2f * di + 8.3333333e-3f * av +
                               1.3888889e-3f * a2v + 1.9841270e-4f * a3v;
                    float b2 = 2.4801587e-5f * di + 2.7557319e-6f * av +
                               2.7557319e-7f * a2v + 2.5052108e-8f * a3v;
                    H0[i] = f2bf(b0); L0[i] = f2bf(b0 - bf2f(H0[i]));
                    H1[i] = f2bf(b1); L1[i] = f2bf(b1 - bf2f(H1[i]));
                    H2[i] = f2bf(b2); L2[i] = f2bf(b2 - bf2f(H2[i]));
                }
                const size_t to = (size_t)gcol * DZ + grow;
                *(ushort4*)&e.B0Th[to] = h0; *(ushort4*)&e.B0Tl[to] = l0;
                *(ushort4*)&e.B1Th[to] = h1v; *(ushort4*)&e.B1Tl[to] = l1v;
                *(ushort4*)&e.B2Th[to] = h2v; *(ushort4*)&e.B2Tl[to] = l2v;
            } else {
                if (in.Dadd) {
#pragma unroll
                    for (int i = 0; i < 4; ++i)
                        a[i] += in.Dadd[(size_t)(grow + i) * N + gcol];
                }
                unsigned short h4[4], l4[4];
#pragma unroll
                for (int i = 0; i < 4; ++i) {
                    h4[i] = f2bf(a[i]);
                    l4[i] = f2bf(a[i] - bf2f(h4[i]));
                }
                if (o.Cf32) {
#pragma unroll
                    for (int i = 0; i < 4; ++i) o.Cf32[(size_t)(grow + i) * N + gcol] = a[i];
                }
                if (o.Chi) {
#pragma unroll
                    for (int i = 0; i < 4; ++i) o.Chi[(size_t)(grow + i) * N + gcol] = h4[i];
                }
                if (o.Clo) {
#pragma unroll
                    for (int i = 0; i < 4; ++i) o.Clo[(size_t)(grow + i) * N + gcol] = l4[i];
                }
                if (o.CThi) {
                    ushort4 u = {h4[0], h4[1], h4[2], h4[3]};
                    *(ushort4*)&o.CThi[(size_t)gcol * M + grow] = u;
                }
                if (o.CTlo) {
                    ushort4 u = {l4[0], l4[1], l4[2], l4[3]};
                    *(ushort4*)&o.CTlo[(size_t)gcol * M + grow] = u;
                }
            }
        }
    }
}

// ---------------------------------------------------------------------------
// Big bf16 MFMA GEMM core (round-8-proven): 64(M)x128(N) tile, BK=32, GLDS16.
// Kept for the combo (XP) dispatch.
template <int RELU, int BIAS, int OUT_BF16>
__device__ __forceinline__ void bigemm_core(int bxi, int byi, int M, int N, int K,
                                            const unsigned short* __restrict__ A,
                                            const unsigned short* __restrict__ B,
                                            void* __restrict__ C,
                                            const float* __restrict__ bias,
                                            unsigned short* As, unsigned short* Bs) {
    const int tid = threadIdx.x;
    const int lane = tid & 63;
    const int wave = tid >> 6;
    const int wr = wave >> 1, wc = wave & 1;
    const int row0 = byi * 64;
    const int col0 = bxi * 128;

    const int srow = lane >> 2;
    const int schunk = (lane & 3) * 8;

    f32x4 acc[2][4] = {};

    for (int k0 = 0; k0 < K; k0 += 32) {
        GLDS16(A + (size_t)(row0 + wave * 16 + srow) * K + k0 + schunk, &As[(wave * 16) * 32]);
        GLDS16(B + (size_t)(col0 + wave * 32 + srow) * K + k0 + schunk, &Bs[(wave * 32) * 32]);
        GLDS16(B + (size_t)(col0 + wave * 32 + 16 + srow) * K + k0 + schunk,
               &Bs[(wave * 32 + 16) * 32]);
        __syncthreads();

        const int kk = (lane >> 4) * 8;
        const int mbase = wr * 32 + (lane & 15);
        const int nbase = wc * 64 + (lane & 15);
        bf16x8 af[2], bf[4];
#pragma unroll
        for (int t = 0; t < 2; ++t) af[t] = *(const bf16x8*)&As[(mbase + t * 16) * 32 + kk];
#pragma unroll
        for (int t = 0; t < 4; ++t) bf[t] = *(const bf16x8*)&Bs[(nbase + t * 16) * 32 + kk];
#pragma unroll
        for (int mt = 0; mt < 2; ++mt)
#pragma unroll
            for (int nt = 0; nt < 4; ++nt)
                acc[mt][nt] = __builtin_amdgcn_mfma_f32_16x16x32_bf16(af[mt], bf[nt],
                                                                      acc[mt][nt], 0, 0, 0);
        __syncthreads();
    }

#pragma unroll
    for (int mt = 0; mt < 2; ++mt) {
        const int grow = row0 + wr * 32 + mt * 16 + (lane >> 4) * 4;
#pragma unroll
        for (int nt = 0; nt < 4; ++nt) {
            const int gcol = col0 + wc * 64 + nt * 16 + (lane & 15);
            const float bv = BIAS ? bias[gcol] : 0.0f;
#pragma unroll
            for (int i = 0; i < 4; ++i) {
                float v = acc[mt][nt][i] + bv;
                if (RELU) v = fmaxf(v, 0.0f);
                const size_t off = (size_t)(grow + i) * N + gcol;
                if (OUT_BF16)
                    ((unsigned short*)C)[off] = f2bf(v);
                else
                    ((float*)C)[off] = v;
            }
        }
    }
}

// ---------------------------------------------------------------------------
// NEW v3: 128x128 tile, BK=64, register-prefetch two-barrier loop (g64-style,
// no GLDS). 4 waves 2x2, each 64x64 (4x4 MFMA grid). Padded LDS (LDT=72).
// C = A @ B^T (+bias)(relu). M%128==0, N%128==0, K%64==0.
template <int RELU, int BIAS, int OUT_BF16>
__global__ __launch_bounds__(256) void gemm_bf16_v3(int M, int N, int K,
                                                    const unsigned short* __restrict__ A,
                                                    const unsigned short* __restrict__ B,
                                                    void* __restrict__ C,
                                                    const float* __restrict__ bias) {
    __shared__ __align__(16) unsigned short As[128 * LDT];
    __shared__ __align__(16) unsigned short Bs[128 * LDT];
    const int tid = threadIdx.x;
    const int lane = tid & 63;
    const int wave = tid >> 6;
    const int wr = wave >> 1, wc = wave & 1;
    const int row0 = blockIdx.y * 128;
    const int col0 = blockIdx.x * 128;
    const int sr = tid >> 1;          // 0..127 (stage row)
    const int sk = (tid & 1) * 32;    // 0 or 32 shorts (half-row)

    const int niter = K >> 6;  // BK=64
    bf16x8 pa[4], pb[4];
    {
        const unsigned short* ar = A + (size_t)(row0 + sr) * K + sk;
        const unsigned short* br = B + (size_t)(col0 + sr) * K + sk;
#pragma unroll
        for (int i = 0; i < 4; ++i) {
            pa[i] = *(const bf16x8*)(ar + 8 * i);
            pb[i] = *(const bf16x8*)(br + 8 * i);
        }
    }

    f32x4 acc[4][4] = {};
    const int mb = wr * 64 + (lane & 15);
    const int nb = wc * 64 + (lane & 15);

    for (int it = 0; it < niter; ++it) {
        __syncthreads();  // prior iteration's LDS consumers done
#pragma unroll
        for (int i = 0; i < 4; ++i) {
            *(bf16x8*)&As[sr * LDT + sk + 8 * i] = pa[i];
            *(bf16x8*)&Bs[sr * LDT + sk + 8 * i] = pb[i];
        }
        __syncthreads();  // publish

        {   // next-iteration prefetch — overlaps the 32 MFMAs below
            const int kn = (it + 1 < niter) ? ((it + 1) << 6) : 0;
            const unsigned short* ar = A + (size_t)(row0 + sr) * K + kn + sk;
            const unsigned short* br = B + (size_t)(col0 + sr) * K + kn + sk;
#pragma unroll
            for (int i = 0; i < 4; ++i) {
                pa[i] = *(const bf16x8*)(ar + 8 * i);
                pb[i] = *(const bf16x8*)(br + 8 * i);
            }
        }

#pragma unroll
        for (int kh = 0; kh < 2; ++kh) {
            const int kk = kh * 32 + (lane >> 4) * 8;
            bf16x8 af[4], bf[4];
#pragma unroll
            for (int t = 0; t < 4; ++t) {
                af[t] = *(const bf16x8*)&As[(mb + t * 16) * LDT + kk];
                bf[t] = *(const bf16x8*)&Bs[(nb + t * 16) * LDT + kk];
            }
#pragma unroll
            for (int mt = 0; mt < 4; ++mt)
#pragma unroll
                for (int nt = 0; nt < 4; ++nt)
                    acc[mt][nt] = __builtin_amdgcn_mfma_f32_16x16x32_bf16(
                        af[mt], bf[nt], acc[mt][nt], 0, 0, 0);
        }
    }

    // epilogue — C/D layout: col=lane&15, row=(lane>>4)*4+reg (proven)
#pragma unroll
    for (int mt = 0; mt < 4; ++mt) {
        const int grow = row0 + wr * 64 + mt * 16 + (lane >> 4) * 4;
#pragma unroll
        for (int nt = 0; nt < 4; ++nt) {
            const int gcol = col0 + wc * 64 + nt * 16 + (lane & 15);
            const float bv = BIAS ? bias[gcol] : 0.0f;
#pragma unroll
            for (int i = 0; i < 4; ++i) {
                float v = acc[mt][nt][i] + bv;
                if (RELU) v = fmaxf(v, 0.0f);
                const size_t off = (size_t)(grow + i) * N + gcol;
                if (OUT_BF16)
                    ((unsigned short*)C)[off] = f2bf(v);
                else
                    ((float*)C)[off] = v;
            }
        }
    }
}

// ---------------------------------------------------------------------------
// combo: z=0 -> XP = X @ P^T (256 blocks); z=1 -> A2 = A@A split+splitT (64).
__global__ __launch_bounds__(256) void combo_k(const unsigned short* Xb,
                                               const unsigned short* Pb,
                                               unsigned short* XPb,
                                               G64In ia, G64Out oa) {
    __shared__ __align__(16) unsigned short smem[4 * 64 * LDT];
    if (blockIdx.z == 0) {
        if (blockIdx.x >= DZ / 128) return;
        bigemm_core<0, 0, 1>(blockIdx.x, blockIdx.y, BDIM, DZ, DX, Xb, Pb, XPb, nullptr,
                             smem, smem + 64 * 32);
    } else {
        if (blockIdx.x >= 8 || blockIdx.y >= 8) return;
        E0Out e = {};
        g64_core<0>(blockIdx.x, blockIdx.y, DZ, DZ, DZ, ia, oa, e,
                    smem, smem + 64 * LDT, smem + 128 * LDT, smem + 192 * LDT);
    }
}

// dual (d2): z0 = A3 = A2@A with fused e0 epilogue; z1 = A4 = A2@A2 -> split+splitT.
__global__ __launch_bounds__(256) void g64_dual_e0(G64In i0, E0Out e0o,
                                                   G64In i1, G64Out o1) {
    __shared__ __align__(16) unsigned short Ash[64 * LDT], Asl[64 * LDT];
    __shared__ __align__(16) unsigned short Bsh[64 * LDT], Bsl[64 * LDT];
    if (blockIdx.z == 0) {
        G64Out on = {};
        g64_core<1>(blockIdx.x, blockIdx.y, DZ, DZ, DZ, i0, on, e0o, Ash, Asl, Bsh, Bsl);
    } else {
        E0Out en = {};
        g64_core<0>(blockIdx.x, blockIdx.y, DZ, DZ, DZ, i1, o1, en, Ash, Asl, Bsh, Bsl);
    }
}

// quad (d3): z in {0,1,2}: U_q = W1 @ B_q (8x32 grid); z=3: A8 = A4@A4 -> splitT (8x8).
__global__ __launch_bounds__(256) void g64_quad(G64In i0, G64Out o0, G64In i1, G64Out o1,
                                                G64In i2, G64Out o2, G64In i3, G64Out o3) {
    __shared__ __align__(16) unsigned short Ash[64 * LDT], Asl[64 * LDT];
    __shared__ __align__(16) unsigned short Bsh[64 * LDT], Bsl[64 * LDT];
    const int z = blockIdx.z;
    if (z == 3 && blockIdx.y >= 8) return;
    G64In in = (z == 0) ? i0 : (z == 1) ? i1 : (z == 2) ? i2 : i3;
    G64Out o = (z == 0) ? o0 : (z == 1) ? o1 : (z == 2) ? o2 : o3;
    const int M = (z < 3) ? HD : DZ;
    E0Out e = {};
    g64_core<0>(blockIdx.x, blockIdx.y, M, DZ, DZ, in, o, e, Ash, Asl, Bsh, Bsl);
}

// d4: C1 = U0 + U1@A4^T' + U2@A8^T'  (dual-K: two kloop passes), bf16-hi out.
__global__ __launch_bounds__(256) void g64_c1(G64In s1, G64In s2,
                                              const float* __restrict__ U0,
                                              unsigned short* __restrict__ C1b) {
    __shared__ __align__(16) unsigned short Ash[64 * LDT], Asl[64 * LDT];
    __shared__ __align__(16) unsigned short Bsh[64 * LDT], Bsl[64 * LDT];
    const int tid = threadIdx.x;
    const int lane = tid & 63;
    const int wave = tid >> 6;
    const int wr = wave >> 1, wc = wave & 1;
    const int row0 = blockIdx.y * 64, col0 = blockIdx.x * 64;
    const int sr = tid >> 2, sk = (tid & 3) * 16;
    const int mb = wr * 32 + (lane & 15);
    const int nb = wc * 32 + (lane & 15);

    f32x4 acc[4] = {};
    g64_kloop(s1, row0, col0, DZ, acc, sr, sk, mb, nb, Ash, Asl, Bsh, Bsl);
    g64_kloop(s2, row0, col0, DZ, acc, sr, sk, mb, nb, Ash, Asl, Bsh, Bsl);

#pragma unroll
    for (int mt = 0; mt < 2; ++mt) {
        const int grow = row0 + wr * 32 + mt * 16 + (lane >> 4) * 4;
#pragma unroll
        for (int nt = 0; nt < 2; ++nt) {
            const int gcol = col0 + wc * 32 + nt * 16 + (lane & 15);
#pragma unroll
            for (int i = 0; i < 4; ++i) {
                const size_t idx = (size_t)(grow + i) * DZ + gcol;
                C1b[idx] = f2bf(acc[mt * 2 + nt][i] + U0[idx]);
            }
        }
    }
}

// ---------------------------------------------------------------------------
// y-GEMM: 64x64 NT bf16, BK=64 + register prefetch + padded LDS, fp32 out+bias.
__global__ __launch_bounds__(256) void gemm64nt_y(int M, int N, int K,
                                                  const unsigned short* __restrict__ A,
                                                  const unsigned short* __restrict__ B,
                                                  float* __restrict__ C,
                                                  const float* __restrict__ bias) {
    __shared__ __align__(16) unsigned short As[64 * LDT];
    __shared__ __align__(16) unsigned short Bs[64 * LDT];
    const int tid = threadIdx.x;
    const int lane = tid & 63;
    const int wave = tid >> 6;
    const int wr = wave >> 1, wc = wave & 1;
    const int row0 = blockIdx.y * 64;
    const int col0 = blockIdx.x * 64;
    const int sr = tid >> 2, sk = (tid & 3) * 16;

    const int niter = K >> 6;
    bf16x8 pa0, pa1, pb0, pb1;
    {
        const unsigned short* ar = A + (size_t)(row0 + sr) * K + sk;
        const unsigned short* br = B + (size_t)(col0 + sr) * K + sk;
        pa0 = *(const bf16x8*)ar; pa1 = *(const bf16x8*)(ar + 8);
        pb0 = *(const bf16x8*)br; pb1 = *(const bf16x8*)(br + 8);
    }

    f32x4 acc[4] = {};
    const int mb = wr * 32 + (lane & 15);
    const int nb = wc * 32 + (lane & 15);

    for (int it = 0; it < niter; ++it) {
        __syncthreads();
        *(bf16x8*)&As[sr * LDT + sk] = pa0; *(bf16x8*)&As[sr * LDT + sk + 8] = pa1;
        *(bf16x8*)&Bs[sr * LDT + sk] = pb0; *(bf16x8*)&Bs[sr * LDT + sk + 8] = pb1;
        __syncthreads();

        {
            const int kn = (it + 1 < niter) ? ((it + 1) << 6) : 0;
            const unsigned short* ar = A + (size_t)(row0 + sr) * K + kn + sk;
            const unsigned short* br = B + (size_t)(col0 + sr) * K + kn + sk;
            pa0 = *(const bf16x8*)ar; pa1 = *(const bf16x8*)(ar + 8);
            pb0 = *(const bf16x8*)br; pb1 = *(const bf16x8*)(br + 8);
        }

#pragma unroll
        for (int kh = 0; kh < 2; ++kh) {
            const int kk = kh * 32 + (lane >> 4) * 8;
            bf16x8 af[2], bf[2];
#pragma unroll
            for (int t = 0; t < 2; ++t) {
                af[t] = *(const bf16x8*)&As[(mb + t * 16) * LDT + kk];
                bf[t] = *(const bf16x8*)&Bs[(nb + t * 16) * LDT + kk];
            }
#pragma unroll
            for (int mt = 0; mt < 2; ++mt)
#pragma unroll
                for (int nt = 0; nt < 2; ++nt)
                    acc[mt * 2 + nt] = __builtin_amdgcn_mfma_f32_16x16x32_bf16(
                        af[mt], bf[nt], acc[mt * 2 + nt], 0, 0, 0);
        }
    }

#pragma unroll
    for (int mt = 0; mt < 2; ++mt) {
        const int grow = row0 + wr * 32 + mt * 16 + (lane >> 4) * 4;
#pragma unroll
        for (int nt = 0; nt < 2; ++nt) {
            const int gcol = col0 + wc * 32 + nt * 16 + (lane & 15);
            const float bv = bias ? bias[gcol] : 0.0f;
#pragma unroll
            for (int i = 0; i < 4; ++i)
                C[(size_t)(grow + i) * N + gcol] = acc[mt * 2 + nt][i] + bv;
        }
    }
}

// ---------------------------------------------------------------------------
extern "C" void kernel_launch(void* const* d_in, const int* in_sizes, int n_in,
                              void* d_out, int out_size, void* d_ws, size_t ws_size,
                              hipStream_t stream) {
    const float* X  = (const float*)d_in[0];  // [B, Dx]
    const float* P  = (const float*)d_in[1];  // [Dz, Dx]
    const float* Am = (const float*)d_in[2];  // [Dz, Dz]
    const float* W1 = (const float*)d_in[3];  // [H, Dz]
    const float* b1 = (const float*)d_in[4];
    const float* W2 = (const float*)d_in[5];  // [H, H]
    const float* b2 = (const float*)d_in[6];
    const float* W3 = (const float*)d_in[7];  // [Dy, H]
    const float* b3 = (const float*)d_in[8];
    float* out = (float*)d_out;               // [B, Dy] fp32

    const size_t S = (size_t)DZ * DZ;       // 262144
    const size_t SW = (size_t)HD * DZ;      // 1048576

    // ---- workspace carve-up (~73.5 MB; U0f aliases dead A/A2 region) ----
    char* p = (char*)d_ws;
    auto alloc_h = [&](size_t n) { unsigned short* r = (unsigned short*)p; p += ((n * 2 + 15) & ~15ull); return r; };
    unsigned short* Xb   = alloc_h((size_t)BDIM * DX);
    unsigned short* W2b  = alloc_h((size_t)HD * HD);
    unsigned short* W3b  = alloc_h((size_t)DY * HD);
    unsigned short* W1h  = alloc_h(SW);
    unsigned short* W1l  = alloc_h(SW);
    unsigned short* Pb   = alloc_h(S);
    unsigned short* Ah   = alloc_h(S);   // |--- dead after d2; U0f aliases group
    unsigned short* Al   = alloc_h(S);
    unsigned short* ATh  = alloc_h(S);
    unsigned short* ATl  = alloc_h(S);
    unsigned short* A2h  = alloc_h(S);
    unsigned short* A2l  = alloc_h(S);
    unsigned short* A2Th = alloc_h(S);
    unsigned short* A2Tl = alloc_h(S);
    unsigned short* A4h  = alloc_h(S);
    unsigned short* A4l  = alloc_h(S);
    unsigned short* A4Th = alloc_h(S);
    unsigned short* A4Tl = alloc_h(S);
    unsigned short* A8Th = alloc_h(S);
    unsigned short* A8Tl = alloc_h(S);
    unsigned short* B0Th = alloc_h(S);
    unsigned short* B0Tl = alloc_h(S);
    unsigned short* B1Th = alloc_h(S);
    unsigned short* B1Tl = alloc_h(S);
    unsigned short* B2Th = alloc_h(S);
    unsigned short* B2Tl = alloc_h(S);
    unsigned short* U1h  = alloc_h(SW);
    unsigned short* U1l  = alloc_h(SW);
    unsigned short* U2h  = alloc_h(SW);
    unsigned short* U2l  = alloc_h(SW);
    unsigned short* C1b  = alloc_h(SW);
    unsigned short* XPb  = alloc_h((size_t)BDIM * DZ);
    unsigned short* h1b  = alloc_h((size_t)BDIM * HD);
    unsigned short* h2b  = alloc_h((size_t)BDIM * HD);
    float* U0f = (float*)Ah;  // 4 MB alias: written in d3, after A/A2 are dead

    // ---- L1: prep — all cvts + A^T transposed split, one dispatch ----
    PrepJobs J;
    J.src[0] = X;  J.hi[0] = Xb;  J.lo[0] = nullptr; J.n4[0] = BDIM * DX / 4;
    J.src[1] = W2; J.hi[1] = W2b; J.lo[1] = nullptr; J.n4[1] = HD * HD / 4;
    J.src[2] = W3; J.hi[2] = W3b; J.lo[2] = nullptr; J.n4[2] = DY * HD / 4;
    J.src[3] = W1; J.hi[3] = W1h; J.lo[3] = W1l;     J.n4[3] = (int)(SW / 4);
    J.src[4] = Am; J.hi[4] = Ah;  J.lo[4] = Al;      J.n4[4] = (int)(S / 4);
    J.src[5] = P;  J.hi[5] = Pb;  J.lo[5] = nullptr; J.n4[5] = (int)(S / 4);
    J.src[6] = Am; J.hi[6] = ATh; J.lo[6] = ATl;     J.n4[6] = 256;
    prep_k<<<dim3(HD * HD / 4 / 256, 7), 256, 0, stream>>>(J);

    // ---- L2: combo { XP = X@P^T (256 blk) || A2 = A@A -> split+splitT (64 blk) } ----
    {
        G64In ia{Ah, Al, ATh, ATl, nullptr};
        G64Out oa{nullptr, A2h, A2l, A2Th, A2Tl};
        combo_k<<<dim3(8, BDIM / 64, 2), 256, 0, stream>>>(Xb, Pb, XPb, ia, oa);
    }
    // ---- L3 (d2): dual { A3 -> fused e0 ; A4 -> split+splitT } ----
    {
        G64In i0{A2h, A2l, ATh, ATl, nullptr};
        E0Out e0o{Am, A2h, A2l, B0Th, B0Tl, B1Th, B1Tl, B2Th, B2Tl};
        G64In i1{A2h, A2l, A2Th, A2Tl, nullptr};
        G64Out o1{nullptr, A4h, A4l, A4Th, A4Tl};
        g64_dual_e0<<<dim3(DZ / 64, DZ / 64, 2), 256, 0, stream>>>(i0, e0o, i1, o1);
    }
    // ---- L4 (d3): quad { U0, U1, U2 = W1@B_q ; A8 = A4@A4 -> splitT } ----
    {
        G64In i0{W1h, W1l, B0Th, B0Tl, nullptr};
        G64Out o0{U0f, nullptr, nullptr, nullptr, nullptr};
        G64In i1{W1h, W1l, B1Th, B1Tl, nullptr};
        G64Out o1{nullptr, U1h, U1l, nullptr, nullptr};
        G64In i2{W1h, W1l, B2Th, B2Tl, nullptr};
        G64Out o2{nullptr, U2h, U2l, nullptr, nullptr};
        G64In i3{A4h, A4l, A4Th, A4Tl, nullptr};
        G64Out o3{nullptr, nullptr, nullptr, A8Th, A8Tl};
        g64_quad<<<dim3(DZ / 64, HD / 64, 4), 256, 0, stream>>>(i0, o0, i1, o1, i2, o2, i3, o3);
    }
    // ---- L5 (d4): C1 = U0 + U1@A4 + U2@A8 = W1·exp(A)  (256 blk, dual-K) ----
    {
        G64In s1{U1h, U1l, A4Th, A4Tl, nullptr};
        G64In s2{U2h, U2l, A8Th, A8Tl, nullptr};
        g64_c1<<<dim3(DZ / 64, HD / 64), 256, 0, stream>>>(s1, s2, U0f, C1b);
    }

    // ---- L6: h1 = relu(XP @ C1^T + b1)  — NEW v3 reg-prefetch 128x128 ----
    gemm_bf16_v3<1, 1, 1><<<dim3(HD / 128, BDIM / 128), 256, 0, stream>>>(
        BDIM, HD, DZ, XPb, C1b, h1b, b1);
    // ---- L7: h2 = relu(h1 @ W2^T + b2) — NEW v3 ----
    gemm_bf16_v3<1, 1, 1><<<dim3(HD / 128, BDIM / 128), 256, 0, stream>>>(
        BDIM, HD, HD, h1b, W2b, h2b, b2);
    // ---- L8: y = h2 @ W3^T + b3 (fp32 out) ----
    gemm64nt_y<<<dim3(DY / 64, BDIM / 64), 256, 0, stream>>>(
        BDIM, DY, HD, h2b, W3b, out, b3);
}